// Round 1
// baseline (1618.718 us; speedup 1.0000x reference)
//
#include <hip/hip_runtime.h>
#include <stdint.h>

typedef unsigned long long u64;
typedef unsigned int u32;

#define NND 20000      // nodes
#define EUA 160000     // directed input edges (2 * E_UND)
#define EFE 80000      // max clean (undirected, deduped) edges
#define ICH 128
#define HIDC 64
#define SCAN_BS 256
#define NB_N ((NND + 255) / 256)
#define NB_EU ((EUA + 255) / 256)
#define NB_EF ((EFE + 255) / 256)
#define NB_E64 ((EFE * HIDC + 255) / 256)
#define NB_X ((NND * ICH + 255) / 256)
#define NSCAN_B ((NND + SCAN_BS - 1) / SCAN_BS)

// scal slots: 0=E, 1=kRem, 2=M, 3=Ep, 4=Ekept, 15=dummy

// ---------------- scan (exclusive, n = NND fixed) ----------------
__global__ void scan1(const int* __restrict__ in, int* __restrict__ out,
                      int* __restrict__ bsums, int n) {
    __shared__ int sh[SCAN_BS];
    int tid = threadIdx.x;
    int i = blockIdx.x * SCAN_BS + tid;
    int v = (i < n) ? in[i] : 0;
    sh[tid] = v;
    __syncthreads();
    for (int o = 1; o < SCAN_BS; o <<= 1) {
        int t = (tid >= o) ? sh[tid - o] : 0;
        __syncthreads();
        sh[tid] += t;
        __syncthreads();
    }
    if (i < n) out[i] = sh[tid] - v;  // exclusive
    if (tid == SCAN_BS - 1) bsums[blockIdx.x] = sh[tid];
}
__global__ void scan2(int* __restrict__ bsums, int nb) {
    __shared__ int sh[160];
    int tid = threadIdx.x;
    if (tid < nb) sh[tid] = bsums[tid];
    __syncthreads();
    if (tid == 0) {
        int acc = 0;
        for (int i = 0; i < nb; i++) { int t = sh[i]; sh[i] = acc; acc += t; }
        sh[nb] = acc;
    }
    __syncthreads();
    if (tid <= nb) bsums[tid] = sh[tid];
}
__global__ void scan3(int* __restrict__ out, const int* __restrict__ bsums,
                      int n, int nb, int* __restrict__ totalDst) {
    int i = blockIdx.x * SCAN_BS + threadIdx.x;
    if (i < n) out[i] += bsums[blockIdx.x];
    if (i == 0) {
        int tot = bsums[nb];
        out[n] = tot;
        *totalDst = tot;
    }
}

// ---------------- clean edge build ----------------
__global__ void kFilterCount(const int* __restrict__ ei, int* __restrict__ cnt) {
    int i = blockIdx.x * 256 + threadIdx.x;
    if (i >= EUA) return;
    int s = ei[i], d = ei[EUA + i];
    if (s < d) atomicAdd(&cnt[s], 1);
}
__global__ void kFilterScatter(const int* __restrict__ ei, const int* __restrict__ offA,
                               int* __restrict__ tmp, int* __restrict__ bucketV) {
    int i = blockIdx.x * 256 + threadIdx.x;
    if (i >= EUA) return;
    int s = ei[i], d = ei[EUA + i];
    if (s < d) {
        int p = offA[s] + atomicAdd(&tmp[s], 1);
        bucketV[p] = d;
    }
}
// insertion sort each segment (small buckets, <=~40)
__global__ void kSortSeg(int* __restrict__ arr, const int* __restrict__ offA) {
    int u = blockIdx.x * 256 + threadIdx.x;
    if (u >= NND) return;
    int s = offA[u], e = offA[u + 1];
    for (int i = s + 1; i < e; i++) {
        int v = arr[i];
        int j = i - 1;
        while (j >= s && arr[j] > v) { arr[j + 1] = arr[j]; j--; }
        arr[j + 1] = v;
    }
}
__global__ void kUniqueCount(const int* __restrict__ arr, const int* __restrict__ offA,
                             int* __restrict__ ucnt) {
    int u = blockIdx.x * 256 + threadIdx.x;
    if (u >= NND) return;
    int s = offA[u], e = offA[u + 1], c = 0;
    for (int i = s; i < e; i++) c += (i == s) || (arr[i] != arr[i - 1]);
    ucnt[u] = c;
}
__global__ void kCompact(const int* __restrict__ arr, const int* __restrict__ offA,
                         const int* __restrict__ uoff, int* __restrict__ eU,
                         int* __restrict__ eV) {
    int u = blockIdx.x * 256 + threadIdx.x;
    if (u >= NND) return;
    int s = offA[u], e = offA[u + 1], o = uoff[u];
    for (int i = s; i < e; i++)
        if (i == s || arr[i] != arr[i - 1]) { eU[o] = u; eV[o] = arr[i]; o++; }
}

// ---------------- incidence CSR ----------------
__global__ void kIncCount(const int* __restrict__ eU, const int* __restrict__ eV,
                          const int* __restrict__ scal, int* __restrict__ icnt) {
    int e = blockIdx.x * 256 + threadIdx.x;
    if (e >= scal[0]) return;
    atomicAdd(&icnt[eU[e]], 1);
    atomicAdd(&icnt[eV[e]], 1);
}
__global__ void kIncScatter(const int* __restrict__ eU, const int* __restrict__ eV,
                            const int* __restrict__ scal, const int* __restrict__ ioff,
                            int* __restrict__ itmp, int* __restrict__ ilist) {
    int e = blockIdx.x * 256 + threadIdx.x;
    if (e >= scal[0]) return;
    int u = eU[e], v = eV[e];
    ilist[ioff[u] + atomicAdd(&itmp[u], 1)] = e;
    ilist[ioff[v] + atomicAdd(&itmp[v], 1)] = e;
}
__global__ void kDinv(const int* __restrict__ eU, const int* __restrict__ eV,
                      const int* __restrict__ icnt, const int* __restrict__ scal,
                      float* __restrict__ dinv) {
    int e = blockIdx.x * 256 + threadIdx.x;
    if (e >= scal[0]) return;
    dinv[e] = rsqrtf((float)(icnt[eU[e]] + icnt[eV[e]] - 1));
}

// ---------------- GEMM: h = (0.5*(x[u]+x[v])) @ W1 ----------------
__global__ void kGemm(const float* __restrict__ x, const float* __restrict__ W1,
                      const int* __restrict__ eU, const int* __restrict__ eV,
                      const int* __restrict__ scal, float* __restrict__ h) {
    __shared__ float xs[ICH];
    int e = blockIdx.x;
    if (e >= scal[0]) return;
    int u = eU[e], v = eV[e];
    for (int k = threadIdx.x; k < ICH; k += HIDC)
        xs[k] = 0.5f * (x[(size_t)u * ICH + k] + x[(size_t)v * ICH + k]);
    __syncthreads();
    float acc = 0.f;
    int c = threadIdx.x;
#pragma unroll 8
    for (int k = 0; k < ICH; k++) acc += xs[k] * W1[k * HIDC + c];
    h[(size_t)e * HIDC + c] = acc;
}

// S[n][c] = sum over incident edges e: h[e][c]*dinv[e]  (deterministic gather)
__global__ void kSGather(const float* __restrict__ h, const float* __restrict__ dinv,
                         const int* __restrict__ ioff, const int* __restrict__ ilist,
                         float* __restrict__ S) {
    int n = blockIdx.x;
    int c = threadIdx.x;
    int s = ioff[n], e = ioff[n + 1];
    float acc = 0.f;
    for (int j = s; j < e; j++) {
        int ed = ilist[j];
        acc += h[(size_t)ed * HIDC + c] * dinv[ed];
    }
    S[(size_t)n * HIDC + c] = acc;
}
__global__ void kConv1(const float* __restrict__ h, const float* __restrict__ S,
                       const float* __restrict__ dinv, const int* __restrict__ eU,
                       const int* __restrict__ eV, const float* __restrict__ b1,
                       const int* __restrict__ scal, float* __restrict__ h2) {
    int idx = blockIdx.x * 256 + threadIdx.x;
    int e = idx >> 6;
    if (e >= scal[0]) return;
    int c = idx & 63;
    float a = dinv[e];
    h2[idx] = a * (S[(size_t)eU[e] * HIDC + c] + S[(size_t)eV[e] * HIDC + c]) -
              a * a * h[idx] + b1[c];
}

// ---------------- mean/var (deterministic two-level) ----------------
__global__ void kRed1(const float* __restrict__ h2, const int* __restrict__ scal,
                      const float* __restrict__ muvar, float* __restrict__ partial,
                      int pass) {
    int g = blockIdx.x, c = threadIdx.x;
    int E = scal[0];
    float m = pass ? muvar[c] : 0.f;
    float acc = 0.f;
    for (int e = g; e < E; e += 256) {
        float v = h2[(size_t)e * HIDC + c];
        if (pass) { float d = v - m; acc += d * d; }
        else acc += v;
    }
    partial[g * HIDC + c] = acc;
}
__global__ void kRed2(const float* __restrict__ partial, const int* __restrict__ scal,
                      float* __restrict__ muvar, int pass) {
    int c = threadIdx.x;
    float acc = 0.f;
    for (int g = 0; g < 256; g++) acc += partial[g * HIDC + c];
    muvar[pass * HIDC + c] = acc / (float)scal[0];
}
__global__ void kNorm(const float* __restrict__ h2, const float* __restrict__ muvar,
                      const float* __restrict__ gamma1, const float* __restrict__ beta1,
                      const int* __restrict__ scal, float* __restrict__ hn) {
    int idx = blockIdx.x * 256 + threadIdx.x;
    int e = idx >> 6;
    if (e >= scal[0]) return;
    int c = idx & 63;
    float t = gamma1[c] * (h2[idx] - muvar[c]) * rsqrtf(muvar[HIDC + c] + 1e-5f) + beta1[c];
    hn[idx] = t > 0.f ? t : 0.f;
}

// ---------------- conv2 (scalar channel) ----------------
__global__ void kZ(const float* __restrict__ hn, const float* __restrict__ W2,
                   const int* __restrict__ scal, float* __restrict__ z) {
    int e = blockIdx.x;
    if (e >= scal[0]) return;
    float p = hn[(size_t)e * HIDC + threadIdx.x] * W2[threadIdx.x];
#pragma unroll
    for (int o = 32; o > 0; o >>= 1) p += __shfl_down(p, o, 64);
    if (threadIdx.x == 0) z[e] = p;
}
__global__ void kS2(const float* __restrict__ z, const float* __restrict__ dinv,
                    const int* __restrict__ ioff, const int* __restrict__ ilist,
                    float* __restrict__ S2) {
    int n = blockIdx.x * 256 + threadIdx.x;
    if (n >= NND) return;
    float acc = 0.f;
    for (int j = ioff[n]; j < ioff[n + 1]; j++) {
        int e = ilist[j];
        acc += z[e] * dinv[e];
    }
    S2[n] = acc;
}
__global__ void kScore(const float* __restrict__ z, const float* __restrict__ S2,
                       const float* __restrict__ dinv, const int* __restrict__ eU,
                       const int* __restrict__ eV, const float* __restrict__ b2,
                       const int* __restrict__ scal, float* __restrict__ score,
                       u64* __restrict__ okey) {
    int e = blockIdx.x * 256 + threadIdx.x;
    if (e >= scal[0]) return;
    float a = dinv[e];
    float l = a * (S2[eU[e]] + S2[eV[e]]) - a * a * z[e] + b2[0];
    float s = 1.f / (1.f + expf(-l));
    score[e] = s;
    u32 b = __float_as_uint(s);
    b = (b >> 31) ? ~b : (b | 0x80000000u);
    okey[e] = (((u64)b) << 32) | (u32)(0xFFFFFFFFu - (u32)e);
}

// ---------------- radix select (k-th largest okey) ----------------
__global__ void kSelInit(const int* __restrict__ scal, int* __restrict__ krem,
                         u64* __restrict__ pref) {
    int E = scal[0];
    int k = E / 2;
    if (k > NND / 2) k = NND / 2;
    if (k < 1) k = 1;
    *krem = k;
    *pref = 0ULL;
}
__global__ void kHist(const u64* __restrict__ okey, const int* __restrict__ scal,
                      int* __restrict__ hist, const u64* __restrict__ pref,
                      u64 maskHi, int shift) {
    int e = blockIdx.x * 256 + threadIdx.x;
    if (e >= scal[0]) return;
    u64 k = okey[e];
    if ((k & maskHi) == *pref)
        atomicAdd(&hist[(int)((k >> shift) & 255ULL)], 1);
}
__global__ void kSelPass(const int* __restrict__ hist, u64* __restrict__ pref,
                         int* __restrict__ krem, int shift) {
    __shared__ int sh[256];
    sh[threadIdx.x] = hist[threadIdx.x];
    __syncthreads();
    if (threadIdx.x == 0) {
        int kr = *krem;
        int cumAbove = 0;
        int b = 255;
        for (; b >= 0; b--) {
            int hcnt = sh[b];
            if (cumAbove + hcnt >= kr) break;
            cumAbove += hcnt;
        }
        if (b < 0) b = 0;
        *krem = kr - cumAbove;
        *pref |= ((u64)b) << shift;
    }
}

// ---------------- clustering ----------------
__global__ void kN2cInit(int* __restrict__ n2c) {
    int n = blockIdx.x * 256 + threadIdx.x;
    if (n < NND) n2c[n] = n;
}
__global__ void kMinKey(const u64* __restrict__ okey, const int* __restrict__ eV,
                        const int* __restrict__ scal, const u64* __restrict__ pref,
                        u64* __restrict__ minOkey) {
    int e = blockIdx.x * 256 + threadIdx.x;
    if (e >= scal[0]) return;
    u64 k = okey[e];
    if (k >= *pref) atomicMin(&minOkey[eV[e]], k);
}
__global__ void kN2cSet(const u64* __restrict__ okey, const int* __restrict__ eU,
                        const int* __restrict__ eV, const int* __restrict__ scal,
                        const u64* __restrict__ pref, const u64* __restrict__ minOkey,
                        int* __restrict__ n2c) {
    int e = blockIdx.x * 256 + threadIdx.x;
    if (e >= scal[0]) return;
    u64 k = okey[e];
    int v = eV[e];
    if (k >= *pref && k == minOkey[v]) n2c[v] = eU[e];
}
__global__ void kPresent(const int* __restrict__ n2c, int* __restrict__ present) {
    int n = blockIdx.x * 256 + threadIdx.x;
    if (n < NND) present[n2c[n]] = 1;
}
__global__ void kNi(const int* __restrict__ n2c, const int* __restrict__ o2n,
                    int* __restrict__ ni) {
    int n = blockIdx.x * 256 + threadIdx.x;
    if (n < NND) ni[n] = o2n[n2c[n]];
}

// ---------------- pooled features ----------------
__global__ void kCcnt(const int* __restrict__ ni, int* __restrict__ ccnt) {
    int n = blockIdx.x * 256 + threadIdx.x;
    if (n < NND) atomicAdd(&ccnt[ni[n]], 1);
}
__global__ void kXacc(const float* __restrict__ x, const int* __restrict__ ni,
                      float* __restrict__ dout) {
    int idx = blockIdx.x * 256 + threadIdx.x;
    if (idx >= NND * ICH) return;
    int n = idx >> 7, c = idx & 127;
    atomicAdd(&dout[(size_t)ni[n] * ICH + c], x[idx]);
}
__global__ void kXdiv(float* __restrict__ dout, const int* __restrict__ ccnt,
                      const int* __restrict__ scal) {
    int idx = blockIdx.x * 256 + threadIdx.x;
    int m = idx >> 7;
    if (m >= scal[2]) return;
    dout[idx] /= (float)ccnt[m];
}

// ---------------- pooled edges ----------------
__global__ void kCEcount(const int* __restrict__ ei, const int* __restrict__ ni,
                         int* __restrict__ ecnt2) {
    int i = blockIdx.x * 256 + threadIdx.x;
    if (i >= EUA) return;
    int a = ni[ei[i]], b = ni[ei[EUA + i]];
    if (a != b) atomicAdd(&ecnt2[a], 1);
}
__global__ void kCEscatter(const int* __restrict__ ei, const int* __restrict__ ni,
                           const int* __restrict__ eoff2, int* __restrict__ etmp2,
                           int* __restrict__ bkD) {
    int i = blockIdx.x * 256 + threadIdx.x;
    if (i >= EUA) return;
    int a = ni[ei[i]], b = ni[ei[EUA + i]];
    if (a != b) {
        int p = eoff2[a] + atomicAdd(&etmp2[a], 1);
        bkD[p] = b;
    }
}
// wave-parallel rank sort per bucket (buckets can reach a few hundred entries)
__global__ void kRankSort(const int* __restrict__ in, int* __restrict__ out,
                          const int* __restrict__ offA, int* __restrict__ ucnt) {
    int a = blockIdx.x;
    int s = offA[a], e = offA[a + 1], len = e - s;
    for (int j = threadIdx.x; j < len; j += 64) {
        int v = in[s + j];
        int r = 0;
        for (int i = 0; i < len; i++) {
            int w = in[s + i];
            r += (w < v) || (w == v && i < j);
        }
        out[s + r] = v;
    }
    __syncthreads();
    int c = 0;
    for (int j = threadIdx.x; j < len; j += 64)
        c += (j == 0) || (out[s + j] != out[s + j - 1]);
#pragma unroll
    for (int o = 32; o > 0; o >>= 1) c += __shfl_down(c, o, 64);
    if (threadIdx.x == 0) ucnt[a] = c;
}
__global__ void kCEwrite(const int* __restrict__ bkD2, const int* __restrict__ offA,
                         const int* __restrict__ ueoff, const int* __restrict__ scal,
                         float* __restrict__ dout) {
    int a = blockIdx.x * 256 + threadIdx.x;
    if (a >= NND) return;
    int s = offA[a], e = offA[a + 1];
    int M = scal[2], Ep = scal[3];
    float* r0 = dout + (size_t)M * ICH;
    float* r1 = r0 + Ep;
    int o = ueoff[a];
    for (int i = s; i < e; i++)
        if (i == s || bkD2[i] != bkD2[i - 1]) {
            r0[o] = (float)a;
            r1[o] = (float)bkD2[i];
            o++;
        }
}

// ---------------- trailing outputs ----------------
__global__ void kBatchPool(const int* __restrict__ batch, const int* __restrict__ present,
                           const int* __restrict__ o2n, const int* __restrict__ scal,
                           float* __restrict__ dout) {
    int n = blockIdx.x * 256 + threadIdx.x;
    if (n >= NND) return;
    if (present[n]) {
        size_t base = (size_t)scal[2] * ICH + 2 * (size_t)scal[3];
        dout[base + o2n[n]] = (float)batch[n];
    }
}
__global__ void kScoresOut(const float* __restrict__ score, const int* __restrict__ scal,
                           float* __restrict__ dout) {
    int e = blockIdx.x * 256 + threadIdx.x;
    if (e >= scal[0]) return;
    size_t base = (size_t)scal[2] * ICH + 2 * (size_t)scal[3] + scal[2];
    dout[base + e] = score[e];
}
__global__ void kNiOut(const int* __restrict__ ni, const int* __restrict__ scal,
                       float* __restrict__ dout) {
    int n = blockIdx.x * 256 + threadIdx.x;
    if (n >= NND) return;
    size_t base = (size_t)scal[2] * ICH + 2 * (size_t)scal[3] + scal[2] + scal[0];
    dout[base + n] = (float)ni[n];
}

extern "C" void kernel_launch(void* const* d_in, const int* in_sizes, int n_in,
                              void* d_out, int out_size, void* d_ws, size_t ws_size,
                              hipStream_t stream) {
    (void)in_sizes; (void)n_in; (void)ws_size;
    const float* x = (const float*)d_in[0];
    const float* W1 = (const float*)d_in[1];
    const float* b1 = (const float*)d_in[2];
    const float* gamma1 = (const float*)d_in[3];
    const float* beta1 = (const float*)d_in[4];
    const float* W2 = (const float*)d_in[5];
    const float* b2 = (const float*)d_in[6];
    const int* ei = (const int*)d_in[7];
    const int* batch = (const int*)d_in[8];
    float* dout = (float*)d_out;

    char* w = (char*)d_ws;
    size_t off = 0;
    auto carve = [&](size_t bytes) -> void* {
        off = (off + 255) & ~(size_t)255;
        void* p = w + off;
        off += bytes;
        return p;
    };
    int* cnt = (int*)carve(NND * 4);
    int* offA = (int*)carve((NND + 2) * 4);
    int* tmp = (int*)carve(NND * 4);
    int* ucnt = (int*)carve(NND * 4);
    int* uoff = (int*)carve((NND + 2) * 4);
    int* icnt = (int*)carve(NND * 4);
    int* ioff = (int*)carve((NND + 2) * 4);
    int* itmp = (int*)carve(NND * 4);
    int* bsums = (int*)carve((NSCAN_B + 2) * 4);
    int* scal = (int*)carve(16 * 4);
    int* hist = (int*)carve(256 * 4);
    int* n2c = (int*)carve(NND * 4);
    int* present = (int*)carve(NND * 4);
    int* o2n = (int*)carve((NND + 2) * 4);
    int* niArr = (int*)carve(NND * 4);
    int* ccnt = (int*)carve(NND * 4);
    int* ecnt2 = (int*)carve(NND * 4);
    int* eoff2 = (int*)carve((NND + 2) * 4);
    int* etmp2 = (int*)carve(NND * 4);
    int* uecnt = (int*)carve(NND * 4);
    int* ueoff = (int*)carve((NND + 2) * 4);
    int* bucketV = (int*)carve(EUA * 4);
    int* eU = (int*)carve(EFE * 4);
    int* eV = (int*)carve(EFE * 4);
    int* ilist = (int*)carve(2 * EFE * 4);
    int* bkD = (int*)carve(EUA * 4);
    int* bkD2 = (int*)carve(EUA * 4);
    u64* okey = (u64*)carve(EFE * 8);
    u64* minOkey = (u64*)carve(NND * 8);
    u64* dpref = (u64*)carve(8);
    float* dinv = (float*)carve(EFE * 4);
    float* h = (float*)carve((size_t)EFE * HIDC * 4);
    float* h2 = (float*)carve((size_t)EFE * HIDC * 4);
    float* Snode = (float*)carve((size_t)NND * HIDC * 4);
    float* partial = (float*)carve(256 * HIDC * 4);
    float* muvar = (float*)carve(128 * 4);
    float* zArr = (float*)carve(EFE * 4);
    float* S2 = (float*)carve(NND * 4);
    float* score = (float*)carve(EFE * 4);

    auto scan = [&](const int* in, int* outp, int* totalDst) {
        scan1<<<NSCAN_B, SCAN_BS, 0, stream>>>(in, outp, bsums, NND);
        scan2<<<1, 128, 0, stream>>>(bsums, NSCAN_B);
        scan3<<<NSCAN_B, SCAN_BS, 0, stream>>>(outp, bsums, NND, NSCAN_B, totalDst);
    };

    // zero state
    hipMemsetAsync(cnt, 0, NND * 4, stream);
    hipMemsetAsync(tmp, 0, NND * 4, stream);
    hipMemsetAsync(icnt, 0, NND * 4, stream);
    hipMemsetAsync(itmp, 0, NND * 4, stream);
    hipMemsetAsync(scal, 0, 16 * 4, stream);

    // clean edge list (sorted by (u,v), deduped)
    kFilterCount<<<NB_EU, 256, 0, stream>>>(ei, cnt);
    scan(cnt, offA, scal + 15);
    kFilterScatter<<<NB_EU, 256, 0, stream>>>(ei, offA, tmp, bucketV);
    kSortSeg<<<NB_N, 256, 0, stream>>>(bucketV, offA);
    kUniqueCount<<<NB_N, 256, 0, stream>>>(bucketV, offA, ucnt);
    scan(ucnt, uoff, scal + 0);  // scal[0] = E
    kCompact<<<NB_N, 256, 0, stream>>>(bucketV, offA, uoff, eU, eV);

    // incidence CSR (sorted -> deterministic gathers)
    kIncCount<<<NB_EF, 256, 0, stream>>>(eU, eV, scal, icnt);
    scan(icnt, ioff, scal + 15);
    kIncScatter<<<NB_EF, 256, 0, stream>>>(eU, eV, scal, ioff, itmp, ilist);
    kSortSeg<<<NB_N, 256, 0, stream>>>(ilist, ioff);
    kDinv<<<NB_EF, 256, 0, stream>>>(eU, eV, icnt, scal, dinv);

    // conv1
    kGemm<<<EFE, HIDC, 0, stream>>>(x, W1, eU, eV, scal, h);
    kSGather<<<NND, HIDC, 0, stream>>>(h, dinv, ioff, ilist, Snode);
    kConv1<<<NB_E64, 256, 0, stream>>>(h, Snode, dinv, eU, eV, b1, scal, h2);

    // batch-norm-ish + relu
    kRed1<<<256, HIDC, 0, stream>>>(h2, scal, muvar, partial, 0);
    kRed2<<<1, HIDC, 0, stream>>>(partial, scal, muvar, 0);
    kRed1<<<256, HIDC, 0, stream>>>(h2, scal, muvar, partial, 1);
    kRed2<<<1, HIDC, 0, stream>>>(partial, scal, muvar, 1);
    kNorm<<<NB_E64, 256, 0, stream>>>(h2, muvar, gamma1, beta1, scal, h);  // hn -> h

    // conv2 -> scores + sortable keys
    kZ<<<EFE, HIDC, 0, stream>>>(h, W2, scal, zArr);
    kS2<<<NB_N, 256, 0, stream>>>(zArr, dinv, ioff, ilist, S2);
    kScore<<<NB_EF, 256, 0, stream>>>(zArr, S2, dinv, eU, eV, b2, scal, score, okey);

    // exact k-th largest via 8x8-bit radix select
    kSelInit<<<1, 1, 0, stream>>>(scal, scal + 1, dpref);
    for (int p = 0; p < 8; p++) {
        int shift = 56 - 8 * p;
        u64 maskHi = (p == 0) ? 0ULL : ((~0ULL) << (shift + 8));
        hipMemsetAsync(hist, 0, 256 * 4, stream);
        kHist<<<NB_EF, 256, 0, stream>>>(okey, scal, hist, dpref, maskHi, shift);
        kSelPass<<<1, 256, 0, stream>>>(hist, dpref, scal + 1, shift);
    }

    // cluster: per-dst last-in-topk-order edge
    hipMemsetAsync(minOkey, 0xFF, NND * 8, stream);
    kMinKey<<<NB_EF, 256, 0, stream>>>(okey, eV, scal, dpref, minOkey);
    kN2cInit<<<NB_N, 256, 0, stream>>>(n2c);
    kN2cSet<<<NB_EF, 256, 0, stream>>>(okey, eU, eV, scal, dpref, minOkey, n2c);
    hipMemsetAsync(present, 0, NND * 4, stream);
    kPresent<<<NB_N, 256, 0, stream>>>(n2c, present);
    scan(present, o2n, scal + 2);  // scal[2] = M
    kNi<<<NB_N, 256, 0, stream>>>(n2c, o2n, niArr);

    // pooled features (x_pool lives at d_out offset 0)
    hipMemsetAsync(d_out, 0, (size_t)out_size * 4, stream);
    hipMemsetAsync(ccnt, 0, NND * 4, stream);
    kCcnt<<<NB_N, 256, 0, stream>>>(niArr, ccnt);
    kXacc<<<NB_X, 256, 0, stream>>>(x, niArr, dout);
    kXdiv<<<NB_X, 256, 0, stream>>>(dout, ccnt, scal);

    // pooled edges
    hipMemsetAsync(ecnt2, 0, NND * 4, stream);
    hipMemsetAsync(etmp2, 0, NND * 4, stream);
    kCEcount<<<NB_EU, 256, 0, stream>>>(ei, niArr, ecnt2);
    scan(ecnt2, eoff2, scal + 4);
    kCEscatter<<<NB_EU, 256, 0, stream>>>(ei, niArr, eoff2, etmp2, bkD);
    kRankSort<<<NND, 64, 0, stream>>>(bkD, bkD2, eoff2, uecnt);
    scan(uecnt, ueoff, scal + 3);  // scal[3] = Ep
    kCEwrite<<<NB_N, 256, 0, stream>>>(bkD2, eoff2, ueoff, scal, dout);

    // batch_pool, scores, ni
    kBatchPool<<<NB_N, 256, 0, stream>>>(batch, present, o2n, scal, dout);
    kScoresOut<<<NB_EF, 256, 0, stream>>>(score, scal, dout);
    kNiOut<<<NB_N, 256, 0, stream>>>(niArr, scal, dout);
}

// Round 2
// 677.201 us; speedup vs baseline: 2.3903x; 2.3903x over previous
//
#include <hip/hip_runtime.h>
#include <stdint.h>

typedef unsigned long long u64;
typedef unsigned int u32;

#define NND 20000      // nodes
#define EUA 160000     // directed input edges (2 * E_UND)
#define EFE 80000      // max clean (undirected, deduped) edges
#define ICH 128
#define HIDC 64
#define SCAN_BS 256
#define NB_N ((NND + 255) / 256)
#define NB_EU ((EUA + 255) / 256)
#define NB_EF ((EFE + 255) / 256)
#define NB_E64 ((EFE * HIDC + 255) / 256)
#define NB_X ((NND * ICH + 255) / 256)
#define NSCAN_B ((NND + SCAN_BS - 1) / SCAN_BS)
#define HIST_BLOCKS 128

// scal slots: 0=E, 1=kRem, 2=M, 3=Ep, 4=Ekept, 15=dummy

// ---------------- scan (exclusive, n = NND fixed) ----------------
__global__ void scan1(const int* __restrict__ in, int* __restrict__ out,
                      int* __restrict__ bsums, int n) {
    __shared__ int sh[SCAN_BS];
    int tid = threadIdx.x;
    int i = blockIdx.x * SCAN_BS + tid;
    int v = (i < n) ? in[i] : 0;
    sh[tid] = v;
    __syncthreads();
    for (int o = 1; o < SCAN_BS; o <<= 1) {
        int t = (tid >= o) ? sh[tid - o] : 0;
        __syncthreads();
        sh[tid] += t;
        __syncthreads();
    }
    if (i < n) out[i] = sh[tid] - v;  // exclusive
    if (tid == SCAN_BS - 1) bsums[blockIdx.x] = sh[tid];
}
__global__ void scan2(int* __restrict__ bsums, int nb) {
    __shared__ int sh[160];
    int tid = threadIdx.x;
    if (tid < nb) sh[tid] = bsums[tid];
    __syncthreads();
    if (tid == 0) {
        int acc = 0;
        for (int i = 0; i < nb; i++) { int t = sh[i]; sh[i] = acc; acc += t; }
        sh[nb] = acc;
    }
    __syncthreads();
    if (tid <= nb) bsums[tid] = sh[tid];
}
__global__ void scan3(int* __restrict__ out, const int* __restrict__ bsums,
                      int n, int nb, int* __restrict__ totalDst) {
    int i = blockIdx.x * SCAN_BS + threadIdx.x;
    if (i < n) out[i] += bsums[blockIdx.x];
    if (i == 0) {
        int tot = bsums[nb];
        out[n] = tot;
        *totalDst = tot;
    }
}

// ---------------- clean edge build ----------------
__global__ void kFilterCount(const int* __restrict__ ei, int* __restrict__ cnt) {
    int i = blockIdx.x * 256 + threadIdx.x;
    if (i >= EUA) return;
    int s = ei[i], d = ei[EUA + i];
    if (s < d) atomicAdd(&cnt[s], 1);
}
__global__ void kFilterScatter(const int* __restrict__ ei, const int* __restrict__ offA,
                               int* __restrict__ tmp, int* __restrict__ bucketV) {
    int i = blockIdx.x * 256 + threadIdx.x;
    if (i >= EUA) return;
    int s = ei[i], d = ei[EUA + i];
    if (s < d) {
        int p = offA[s] + atomicAdd(&tmp[s], 1);
        bucketV[p] = d;
    }
}
// insertion sort each segment (small buckets, <=~40)
__global__ void kSortSeg(int* __restrict__ arr, const int* __restrict__ offA) {
    int u = blockIdx.x * 256 + threadIdx.x;
    if (u >= NND) return;
    int s = offA[u], e = offA[u + 1];
    for (int i = s + 1; i < e; i++) {
        int v = arr[i];
        int j = i - 1;
        while (j >= s && arr[j] > v) { arr[j + 1] = arr[j]; j--; }
        arr[j + 1] = v;
    }
}
__global__ void kUniqueCount(const int* __restrict__ arr, const int* __restrict__ offA,
                             int* __restrict__ ucnt) {
    int u = blockIdx.x * 256 + threadIdx.x;
    if (u >= NND) return;
    int s = offA[u], e = offA[u + 1], c = 0;
    for (int i = s; i < e; i++) c += (i == s) || (arr[i] != arr[i - 1]);
    ucnt[u] = c;
}
__global__ void kCompact(const int* __restrict__ arr, const int* __restrict__ offA,
                         const int* __restrict__ uoff, int* __restrict__ eU,
                         int* __restrict__ eV) {
    int u = blockIdx.x * 256 + threadIdx.x;
    if (u >= NND) return;
    int s = offA[u], e = offA[u + 1], o = uoff[u];
    for (int i = s; i < e; i++)
        if (i == s || arr[i] != arr[i - 1]) { eU[o] = u; eV[o] = arr[i]; o++; }
}

// ---------------- incidence CSR ----------------
__global__ void kIncCount(const int* __restrict__ eU, const int* __restrict__ eV,
                          const int* __restrict__ scal, int* __restrict__ icnt) {
    int e = blockIdx.x * 256 + threadIdx.x;
    if (e >= scal[0]) return;
    atomicAdd(&icnt[eU[e]], 1);
    atomicAdd(&icnt[eV[e]], 1);
}
__global__ void kIncScatter(const int* __restrict__ eU, const int* __restrict__ eV,
                            const int* __restrict__ scal, const int* __restrict__ ioff,
                            int* __restrict__ itmp, int* __restrict__ ilist) {
    int e = blockIdx.x * 256 + threadIdx.x;
    if (e >= scal[0]) return;
    int u = eU[e], v = eV[e];
    ilist[ioff[u] + atomicAdd(&itmp[u], 1)] = e;
    ilist[ioff[v] + atomicAdd(&itmp[v], 1)] = e;
}
__global__ void kDinv(const int* __restrict__ eU, const int* __restrict__ eV,
                      const int* __restrict__ icnt, const int* __restrict__ scal,
                      float* __restrict__ dinv) {
    int e = blockIdx.x * 256 + threadIdx.x;
    if (e >= scal[0]) return;
    dinv[e] = rsqrtf((float)(icnt[eU[e]] + icnt[eV[e]] - 1));
}

// ---------------- GEMM: h = (0.5*(x[u]+x[v])) @ W1 ----------------
__global__ void kGemm(const float* __restrict__ x, const float* __restrict__ W1,
                      const int* __restrict__ eU, const int* __restrict__ eV,
                      const int* __restrict__ scal, float* __restrict__ h) {
    __shared__ float xs[ICH];
    int e = blockIdx.x;
    if (e >= scal[0]) return;
    int u = eU[e], v = eV[e];
    for (int k = threadIdx.x; k < ICH; k += HIDC)
        xs[k] = 0.5f * (x[(size_t)u * ICH + k] + x[(size_t)v * ICH + k]);
    __syncthreads();
    float acc = 0.f;
    int c = threadIdx.x;
#pragma unroll 8
    for (int k = 0; k < ICH; k++) acc += xs[k] * W1[k * HIDC + c];
    h[(size_t)e * HIDC + c] = acc;
}

// S[n][c] = sum over incident edges e: h[e][c]*dinv[e]  (deterministic gather)
__global__ void kSGather(const float* __restrict__ h, const float* __restrict__ dinv,
                         const int* __restrict__ ioff, const int* __restrict__ ilist,
                         float* __restrict__ S) {
    int n = blockIdx.x;
    int c = threadIdx.x;
    int s = ioff[n], e = ioff[n + 1];
    float acc = 0.f;
    for (int j = s; j < e; j++) {
        int ed = ilist[j];
        acc += h[(size_t)ed * HIDC + c] * dinv[ed];
    }
    S[(size_t)n * HIDC + c] = acc;
}
__global__ void kConv1(const float* __restrict__ h, const float* __restrict__ S,
                       const float* __restrict__ dinv, const int* __restrict__ eU,
                       const int* __restrict__ eV, const float* __restrict__ b1,
                       const int* __restrict__ scal, float* __restrict__ h2) {
    int idx = blockIdx.x * 256 + threadIdx.x;
    int e = idx >> 6;
    if (e >= scal[0]) return;
    int c = idx & 63;
    float a = dinv[e];
    h2[idx] = a * (S[(size_t)eU[e] * HIDC + c] + S[(size_t)eV[e] * HIDC + c]) -
              a * a * h[idx] + b1[c];
}

// ---------------- mean/var (deterministic two-level) ----------------
__global__ void kRed1(const float* __restrict__ h2, const int* __restrict__ scal,
                      const float* __restrict__ muvar, float* __restrict__ partial,
                      int pass) {
    int g = blockIdx.x, c = threadIdx.x;
    int E = scal[0];
    float m = pass ? muvar[c] : 0.f;
    float acc = 0.f;
    for (int e = g; e < E; e += 256) {
        float v = h2[(size_t)e * HIDC + c];
        if (pass) { float d = v - m; acc += d * d; }
        else acc += v;
    }
    partial[g * HIDC + c] = acc;
}
__global__ void kRed2(const float* __restrict__ partial, const int* __restrict__ scal,
                      float* __restrict__ muvar, int pass) {
    int c = threadIdx.x;
    float acc = 0.f;
    for (int g = 0; g < 256; g++) acc += partial[g * HIDC + c];
    muvar[pass * HIDC + c] = acc / (float)scal[0];
}
__global__ void kNorm(const float* __restrict__ h2, const float* __restrict__ muvar,
                      const float* __restrict__ gamma1, const float* __restrict__ beta1,
                      const int* __restrict__ scal, float* __restrict__ hn) {
    int idx = blockIdx.x * 256 + threadIdx.x;
    int e = idx >> 6;
    if (e >= scal[0]) return;
    int c = idx & 63;
    float t = gamma1[c] * (h2[idx] - muvar[c]) * rsqrtf(muvar[HIDC + c] + 1e-5f) + beta1[c];
    hn[idx] = t > 0.f ? t : 0.f;
}

// ---------------- conv2 (scalar channel) ----------------
__global__ void kZ(const float* __restrict__ hn, const float* __restrict__ W2,
                   const int* __restrict__ scal, float* __restrict__ z) {
    int e = blockIdx.x;
    if (e >= scal[0]) return;
    float p = hn[(size_t)e * HIDC + threadIdx.x] * W2[threadIdx.x];
#pragma unroll
    for (int o = 32; o > 0; o >>= 1) p += __shfl_down(p, o, 64);
    if (threadIdx.x == 0) z[e] = p;
}
__global__ void kS2(const float* __restrict__ z, const float* __restrict__ dinv,
                    const int* __restrict__ ioff, const int* __restrict__ ilist,
                    float* __restrict__ S2) {
    int n = blockIdx.x * 256 + threadIdx.x;
    if (n >= NND) return;
    float acc = 0.f;
    for (int j = ioff[n]; j < ioff[n + 1]; j++) {
        int e = ilist[j];
        acc += z[e] * dinv[e];
    }
    S2[n] = acc;
}
__global__ void kScore(const float* __restrict__ z, const float* __restrict__ S2,
                       const float* __restrict__ dinv, const int* __restrict__ eU,
                       const int* __restrict__ eV, const float* __restrict__ b2,
                       const int* __restrict__ scal, float* __restrict__ score,
                       u64* __restrict__ okey) {
    int e = blockIdx.x * 256 + threadIdx.x;
    if (e >= scal[0]) return;
    float a = dinv[e];
    float l = a * (S2[eU[e]] + S2[eV[e]]) - a * a * z[e] + b2[0];
    float s = 1.f / (1.f + expf(-l));
    score[e] = s;
    u32 b = __float_as_uint(s);
    b = (b >> 31) ? ~b : (b | 0x80000000u);
    okey[e] = (((u64)b) << 32) | (u32)(0xFFFFFFFFu - (u32)e);
}

// ---------------- radix select (k-th largest okey) ----------------
__global__ void kSelInit(const int* __restrict__ scal, int* __restrict__ krem,
                         u64* __restrict__ pref) {
    int E = scal[0];
    int k = E / 2;
    if (k > NND / 2) k = NND / 2;
    if (k < 1) k = 1;
    *krem = k;
    *pref = 0ULL;
}
// LDS-aggregated histogram: per-block 256-bin LDS hist, one global atomic
// per bin per block. Kills the same-address global-atomic serialization
// (sigmoid scores cluster -> most keys share the top byte).
__global__ void kHist(const u64* __restrict__ okey, const int* __restrict__ scal,
                      int* __restrict__ hist, const u64* __restrict__ pref,
                      u64 maskHi, int shift) {
    __shared__ int sh[256];
    sh[threadIdx.x] = 0;
    __syncthreads();
    int E = scal[0];
    u64 p = *pref;
    for (int e = blockIdx.x * 256 + threadIdx.x; e < E; e += HIST_BLOCKS * 256) {
        u64 k = okey[e];
        if ((k & maskHi) == p)
            atomicAdd(&sh[(int)((k >> shift) & 255ULL)], 1);
    }
    __syncthreads();
    int v = sh[threadIdx.x];
    if (v) atomicAdd(&hist[threadIdx.x], v);
}
// consumes hist, then zeroes it for the next pass (saves 8 memsets)
__global__ void kSelPass(int* __restrict__ hist, u64* __restrict__ pref,
                         int* __restrict__ krem, int shift) {
    __shared__ int sh[256];
    sh[threadIdx.x] = hist[threadIdx.x];
    __syncthreads();
    hist[threadIdx.x] = 0;
    if (threadIdx.x == 0) {
        int kr = *krem;
        int cumAbove = 0;
        int b = 255;
        for (; b >= 0; b--) {
            int hcnt = sh[b];
            if (cumAbove + hcnt >= kr) break;
            cumAbove += hcnt;
        }
        if (b < 0) b = 0;
        *krem = kr - cumAbove;
        *pref |= ((u64)b) << shift;
    }
}

// ---------------- clustering ----------------
__global__ void kN2cInit(int* __restrict__ n2c) {
    int n = blockIdx.x * 256 + threadIdx.x;
    if (n < NND) n2c[n] = n;
}
__global__ void kMinKey(const u64* __restrict__ okey, const int* __restrict__ eV,
                        const int* __restrict__ scal, const u64* __restrict__ pref,
                        u64* __restrict__ minOkey) {
    int e = blockIdx.x * 256 + threadIdx.x;
    if (e >= scal[0]) return;
    u64 k = okey[e];
    if (k >= *pref) atomicMin(&minOkey[eV[e]], k);
}
__global__ void kN2cSet(const u64* __restrict__ okey, const int* __restrict__ eU,
                        const int* __restrict__ eV, const int* __restrict__ scal,
                        const u64* __restrict__ pref, const u64* __restrict__ minOkey,
                        int* __restrict__ n2c) {
    int e = blockIdx.x * 256 + threadIdx.x;
    if (e >= scal[0]) return;
    u64 k = okey[e];
    int v = eV[e];
    if (k >= *pref && k == minOkey[v]) n2c[v] = eU[e];
}
__global__ void kPresent(const int* __restrict__ n2c, int* __restrict__ present) {
    int n = blockIdx.x * 256 + threadIdx.x;
    if (n < NND) present[n2c[n]] = 1;
}
__global__ void kNi(const int* __restrict__ n2c, const int* __restrict__ o2n,
                    int* __restrict__ ni) {
    int n = blockIdx.x * 256 + threadIdx.x;
    if (n < NND) ni[n] = o2n[n2c[n]];
}

// ---------------- pooled features ----------------
__global__ void kCcnt(const int* __restrict__ ni, int* __restrict__ ccnt) {
    int n = blockIdx.x * 256 + threadIdx.x;
    if (n < NND) atomicAdd(&ccnt[ni[n]], 1);
}
__global__ void kXacc(const float* __restrict__ x, const int* __restrict__ ni,
                      float* __restrict__ dout) {
    int idx = blockIdx.x * 256 + threadIdx.x;
    if (idx >= NND * ICH) return;
    int n = idx >> 7, c = idx & 127;
    atomicAdd(&dout[(size_t)ni[n] * ICH + c], x[idx]);
}
__global__ void kXdiv(float* __restrict__ dout, const int* __restrict__ ccnt,
                      const int* __restrict__ scal) {
    int idx = blockIdx.x * 256 + threadIdx.x;
    int m = idx >> 7;
    if (m >= scal[2]) return;
    dout[idx] /= (float)ccnt[m];
}

// ---------------- pooled edges ----------------
__global__ void kCEcount(const int* __restrict__ ei, const int* __restrict__ ni,
                         int* __restrict__ ecnt2) {
    int i = blockIdx.x * 256 + threadIdx.x;
    if (i >= EUA) return;
    int a = ni[ei[i]], b = ni[ei[EUA + i]];
    if (a != b) atomicAdd(&ecnt2[a], 1);
}
__global__ void kCEscatter(const int* __restrict__ ei, const int* __restrict__ ni,
                           const int* __restrict__ eoff2, int* __restrict__ etmp2,
                           int* __restrict__ bkD) {
    int i = blockIdx.x * 256 + threadIdx.x;
    if (i >= EUA) return;
    int a = ni[ei[i]], b = ni[ei[EUA + i]];
    if (a != b) {
        int p = eoff2[a] + atomicAdd(&etmp2[a], 1);
        bkD[p] = b;
    }
}
// wave-parallel rank sort per bucket (buckets can reach a few hundred entries)
__global__ void kRankSort(const int* __restrict__ in, int* __restrict__ out,
                          const int* __restrict__ offA, int* __restrict__ ucnt) {
    int a = blockIdx.x;
    int s = offA[a], e = offA[a + 1], len = e - s;
    for (int j = threadIdx.x; j < len; j += 64) {
        int v = in[s + j];
        int r = 0;
        for (int i = 0; i < len; i++) {
            int w = in[s + i];
            r += (w < v) || (w == v && i < j);
        }
        out[s + r] = v;
    }
    __syncthreads();
    int c = 0;
    for (int j = threadIdx.x; j < len; j += 64)
        c += (j == 0) || (out[s + j] != out[s + j - 1]);
#pragma unroll
    for (int o = 32; o > 0; o >>= 1) c += __shfl_down(c, o, 64);
    if (threadIdx.x == 0) ucnt[a] = c;
}
__global__ void kCEwrite(const int* __restrict__ bkD2, const int* __restrict__ offA,
                         const int* __restrict__ ueoff, const int* __restrict__ scal,
                         float* __restrict__ dout) {
    int a = blockIdx.x * 256 + threadIdx.x;
    if (a >= NND) return;
    int s = offA[a], e = offA[a + 1];
    int M = scal[2], Ep = scal[3];
    float* r0 = dout + (size_t)M * ICH;
    float* r1 = r0 + Ep;
    int o = ueoff[a];
    for (int i = s; i < e; i++)
        if (i == s || bkD2[i] != bkD2[i - 1]) {
            r0[o] = (float)a;
            r1[o] = (float)bkD2[i];
            o++;
        }
}

// ---------------- trailing outputs ----------------
__global__ void kBatchPool(const int* __restrict__ batch, const int* __restrict__ present,
                           const int* __restrict__ o2n, const int* __restrict__ scal,
                           float* __restrict__ dout) {
    int n = blockIdx.x * 256 + threadIdx.x;
    if (n >= NND) return;
    if (present[n]) {
        size_t base = (size_t)scal[2] * ICH + 2 * (size_t)scal[3];
        dout[base + o2n[n]] = (float)batch[n];
    }
}
__global__ void kScoresOut(const float* __restrict__ score, const int* __restrict__ scal,
                           float* __restrict__ dout) {
    int e = blockIdx.x * 256 + threadIdx.x;
    if (e >= scal[0]) return;
    size_t base = (size_t)scal[2] * ICH + 2 * (size_t)scal[3] + scal[2];
    dout[base + e] = score[e];
}
__global__ void kNiOut(const int* __restrict__ ni, const int* __restrict__ scal,
                       float* __restrict__ dout) {
    int n = blockIdx.x * 256 + threadIdx.x;
    if (n >= NND) return;
    size_t base = (size_t)scal[2] * ICH + 2 * (size_t)scal[3] + scal[2] + scal[0];
    dout[base + n] = (float)ni[n];
}

extern "C" void kernel_launch(void* const* d_in, const int* in_sizes, int n_in,
                              void* d_out, int out_size, void* d_ws, size_t ws_size,
                              hipStream_t stream) {
    (void)in_sizes; (void)n_in; (void)ws_size;
    const float* x = (const float*)d_in[0];
    const float* W1 = (const float*)d_in[1];
    const float* b1 = (const float*)d_in[2];
    const float* gamma1 = (const float*)d_in[3];
    const float* beta1 = (const float*)d_in[4];
    const float* W2 = (const float*)d_in[5];
    const float* b2 = (const float*)d_in[6];
    const int* ei = (const int*)d_in[7];
    const int* batch = (const int*)d_in[8];
    float* dout = (float*)d_out;

    char* w = (char*)d_ws;
    size_t off = 0;
    auto carve = [&](size_t bytes) -> void* {
        off = (off + 255) & ~(size_t)255;
        void* p = w + off;
        off += bytes;
        return p;
    };
    int* cnt = (int*)carve(NND * 4);
    int* offA = (int*)carve((NND + 2) * 4);
    int* tmp = (int*)carve(NND * 4);
    int* ucnt = (int*)carve(NND * 4);
    int* uoff = (int*)carve((NND + 2) * 4);
    int* icnt = (int*)carve(NND * 4);
    int* ioff = (int*)carve((NND + 2) * 4);
    int* itmp = (int*)carve(NND * 4);
    int* bsums = (int*)carve((NSCAN_B + 2) * 4);
    int* scal = (int*)carve(16 * 4);
    int* hist = (int*)carve(256 * 4);
    int* n2c = (int*)carve(NND * 4);
    int* present = (int*)carve(NND * 4);
    int* o2n = (int*)carve((NND + 2) * 4);
    int* niArr = (int*)carve(NND * 4);
    int* ccnt = (int*)carve(NND * 4);
    int* ecnt2 = (int*)carve(NND * 4);
    int* eoff2 = (int*)carve((NND + 2) * 4);
    int* etmp2 = (int*)carve(NND * 4);
    int* uecnt = (int*)carve(NND * 4);
    int* ueoff = (int*)carve((NND + 2) * 4);
    int* bucketV = (int*)carve(EUA * 4);
    int* eU = (int*)carve(EFE * 4);
    int* eV = (int*)carve(EFE * 4);
    int* ilist = (int*)carve(2 * EFE * 4);
    int* bkD = (int*)carve(EUA * 4);
    int* bkD2 = (int*)carve(EUA * 4);
    u64* okey = (u64*)carve(EFE * 8);
    u64* minOkey = (u64*)carve(NND * 8);
    u64* dpref = (u64*)carve(8);
    float* dinv = (float*)carve(EFE * 4);
    float* h = (float*)carve((size_t)EFE * HIDC * 4);
    float* h2 = (float*)carve((size_t)EFE * HIDC * 4);
    float* Snode = (float*)carve((size_t)NND * HIDC * 4);
    float* partial = (float*)carve(256 * HIDC * 4);
    float* muvar = (float*)carve(128 * 4);
    float* zArr = (float*)carve(EFE * 4);
    float* S2 = (float*)carve(NND * 4);
    float* score = (float*)carve(EFE * 4);

    auto scan = [&](const int* in, int* outp, int* totalDst) {
        scan1<<<NSCAN_B, SCAN_BS, 0, stream>>>(in, outp, bsums, NND);
        scan2<<<1, 128, 0, stream>>>(bsums, NSCAN_B);
        scan3<<<NSCAN_B, SCAN_BS, 0, stream>>>(outp, bsums, NND, NSCAN_B, totalDst);
    };

    // zero state
    hipMemsetAsync(cnt, 0, NND * 4, stream);
    hipMemsetAsync(tmp, 0, NND * 4, stream);
    hipMemsetAsync(icnt, 0, NND * 4, stream);
    hipMemsetAsync(itmp, 0, NND * 4, stream);
    hipMemsetAsync(scal, 0, 16 * 4, stream);
    hipMemsetAsync(hist, 0, 256 * 4, stream);

    // clean edge list (sorted by (u,v), deduped)
    kFilterCount<<<NB_EU, 256, 0, stream>>>(ei, cnt);
    scan(cnt, offA, scal + 15);
    kFilterScatter<<<NB_EU, 256, 0, stream>>>(ei, offA, tmp, bucketV);
    kSortSeg<<<NB_N, 256, 0, stream>>>(bucketV, offA);
    kUniqueCount<<<NB_N, 256, 0, stream>>>(bucketV, offA, ucnt);
    scan(ucnt, uoff, scal + 0);  // scal[0] = E
    kCompact<<<NB_N, 256, 0, stream>>>(bucketV, offA, uoff, eU, eV);

    // incidence CSR (sorted -> deterministic gathers)
    kIncCount<<<NB_EF, 256, 0, stream>>>(eU, eV, scal, icnt);
    scan(icnt, ioff, scal + 15);
    kIncScatter<<<NB_EF, 256, 0, stream>>>(eU, eV, scal, ioff, itmp, ilist);
    kSortSeg<<<NB_N, 256, 0, stream>>>(ilist, ioff);
    kDinv<<<NB_EF, 256, 0, stream>>>(eU, eV, icnt, scal, dinv);

    // conv1
    kGemm<<<EFE, HIDC, 0, stream>>>(x, W1, eU, eV, scal, h);
    kSGather<<<NND, HIDC, 0, stream>>>(h, dinv, ioff, ilist, Snode);
    kConv1<<<NB_E64, 256, 0, stream>>>(h, Snode, dinv, eU, eV, b1, scal, h2);

    // batch-norm-ish + relu
    kRed1<<<256, HIDC, 0, stream>>>(h2, scal, muvar, partial, 0);
    kRed2<<<1, HIDC, 0, stream>>>(partial, scal, muvar, 0);
    kRed1<<<256, HIDC, 0, stream>>>(h2, scal, muvar, partial, 1);
    kRed2<<<1, HIDC, 0, stream>>>(partial, scal, muvar, 1);
    kNorm<<<NB_E64, 256, 0, stream>>>(h2, muvar, gamma1, beta1, scal, h);  // hn -> h

    // conv2 -> scores + sortable keys
    kZ<<<EFE, HIDC, 0, stream>>>(h, W2, scal, zArr);
    kS2<<<NB_N, 256, 0, stream>>>(zArr, dinv, ioff, ilist, S2);
    kScore<<<NB_EF, 256, 0, stream>>>(zArr, S2, dinv, eU, eV, b2, scal, score, okey);

    // exact k-th largest via 8x8-bit radix select (LDS-aggregated histogram;
    // kSelPass zeroes hist for the next pass)
    kSelInit<<<1, 1, 0, stream>>>(scal, scal + 1, dpref);
    for (int p = 0; p < 8; p++) {
        int shift = 56 - 8 * p;
        u64 maskHi = (p == 0) ? 0ULL : ((~0ULL) << (shift + 8));
        kHist<<<HIST_BLOCKS, 256, 0, stream>>>(okey, scal, hist, dpref, maskHi, shift);
        kSelPass<<<1, 256, 0, stream>>>(hist, dpref, scal + 1, shift);
    }

    // cluster: per-dst last-in-topk-order edge
    hipMemsetAsync(minOkey, 0xFF, NND * 8, stream);
    kMinKey<<<NB_EF, 256, 0, stream>>>(okey, eV, scal, dpref, minOkey);
    kN2cInit<<<NB_N, 256, 0, stream>>>(n2c);
    kN2cSet<<<NB_EF, 256, 0, stream>>>(okey, eU, eV, scal, dpref, minOkey, n2c);
    hipMemsetAsync(present, 0, NND * 4, stream);
    kPresent<<<NB_N, 256, 0, stream>>>(n2c, present);
    scan(present, o2n, scal + 2);  // scal[2] = M
    kNi<<<NB_N, 256, 0, stream>>>(n2c, o2n, niArr);

    // pooled features (x_pool lives at d_out offset 0)
    hipMemsetAsync(d_out, 0, (size_t)out_size * 4, stream);
    hipMemsetAsync(ccnt, 0, NND * 4, stream);
    kCcnt<<<NB_N, 256, 0, stream>>>(niArr, ccnt);
    kXacc<<<NB_X, 256, 0, stream>>>(x, niArr, dout);
    kXdiv<<<NB_X, 256, 0, stream>>>(dout, ccnt, scal);

    // pooled edges
    hipMemsetAsync(ecnt2, 0, NND * 4, stream);
    hipMemsetAsync(etmp2, 0, NND * 4, stream);
    kCEcount<<<NB_EU, 256, 0, stream>>>(ei, niArr, ecnt2);
    scan(ecnt2, eoff2, scal + 4);
    kCEscatter<<<NB_EU, 256, 0, stream>>>(ei, niArr, eoff2, etmp2, bkD);
    kRankSort<<<NND, 64, 0, stream>>>(bkD, bkD2, eoff2, uecnt);
    scan(uecnt, ueoff, scal + 3);  // scal[3] = Ep
    kCEwrite<<<NB_N, 256, 0, stream>>>(bkD2, eoff2, ueoff, scal, dout);

    // batch_pool, scores, ni
    kBatchPool<<<NB_N, 256, 0, stream>>>(batch, present, o2n, scal, dout);
    kScoresOut<<<NB_EF, 256, 0, stream>>>(score, scal, dout);
    kNiOut<<<NB_N, 256, 0, stream>>>(niArr, scal, dout);
}

// Round 3
// 597.153 us; speedup vs baseline: 2.7107x; 1.1340x over previous
//
#include <hip/hip_runtime.h>
#include <stdint.h>

typedef unsigned long long u64;
typedef unsigned int u32;

#define NND 20000      // nodes
#define EUA 160000     // directed input edges (2 * E_UND)
#define EFE 80000      // max clean (undirected, deduped) edges
#define ICH 128
#define HIDC 64
#define SCAN_BS 256
#define NB_N ((NND + 255) / 256)
#define NB_EU ((EUA + 255) / 256)
#define NB_EF ((EFE + 255) / 256)
#define NB_E64 ((EFE * HIDC + 255) / 256)
#define NB_X ((NND * ICH + 255) / 256)
#define NSCAN_B ((NND + SCAN_BS - 1) / SCAN_BS)
#define HIST_BLOCKS 128
#define GEB 64         // edges per gemm block
#define XS_PAD 132     // xs leading-dim pad (bank-conflict-free for 4-edge groups)

// scal slots: 0=E, 1=kRem, 2=M, 3=Ep, 4=Ekept, 15=dummy

// ---------------- scan (exclusive, n = NND fixed) ----------------
__global__ void scan1(const int* __restrict__ in, int* __restrict__ out,
                      int* __restrict__ bsums, int n) {
    __shared__ int sh[SCAN_BS];
    int tid = threadIdx.x;
    int i = blockIdx.x * SCAN_BS + tid;
    int v = (i < n) ? in[i] : 0;
    sh[tid] = v;
    __syncthreads();
    for (int o = 1; o < SCAN_BS; o <<= 1) {
        int t = (tid >= o) ? sh[tid - o] : 0;
        __syncthreads();
        sh[tid] += t;
        __syncthreads();
    }
    if (i < n) out[i] = sh[tid] - v;  // exclusive
    if (tid == SCAN_BS - 1) bsums[blockIdx.x] = sh[tid];
}
__global__ void scan2(int* __restrict__ bsums, int nb) {
    __shared__ int sh[160];
    int tid = threadIdx.x;
    if (tid < nb) sh[tid] = bsums[tid];
    __syncthreads();
    if (tid == 0) {
        int acc = 0;
        for (int i = 0; i < nb; i++) { int t = sh[i]; sh[i] = acc; acc += t; }
        sh[nb] = acc;
    }
    __syncthreads();
    if (tid <= nb) bsums[tid] = sh[tid];
}
__global__ void scan3(int* __restrict__ out, const int* __restrict__ bsums,
                      int n, int nb, int* __restrict__ totalDst) {
    int i = blockIdx.x * SCAN_BS + threadIdx.x;
    if (i < n) out[i] += bsums[blockIdx.x];
    if (i == 0) {
        int tot = bsums[nb];
        out[n] = tot;
        *totalDst = tot;
    }
}

// ---------------- clean edge build ----------------
__global__ void kFilterCount(const int* __restrict__ ei, int* __restrict__ cnt) {
    int i = blockIdx.x * 256 + threadIdx.x;
    if (i >= EUA) return;
    int s = ei[i], d = ei[EUA + i];
    if (s < d) atomicAdd(&cnt[s], 1);
}
__global__ void kFilterScatter(const int* __restrict__ ei, const int* __restrict__ offA,
                               int* __restrict__ tmp, int* __restrict__ bucketV) {
    int i = blockIdx.x * 256 + threadIdx.x;
    if (i >= EUA) return;
    int s = ei[i], d = ei[EUA + i];
    if (s < d) {
        int p = offA[s] + atomicAdd(&tmp[s], 1);
        bucketV[p] = d;
    }
}
// insertion sort each segment (small buckets)
__global__ void kSortSeg(int* __restrict__ arr, const int* __restrict__ offA) {
    int u = blockIdx.x * 256 + threadIdx.x;
    if (u >= NND) return;
    int s = offA[u], e = offA[u + 1];
    for (int i = s + 1; i < e; i++) {
        int v = arr[i];
        int j = i - 1;
        while (j >= s && arr[j] > v) { arr[j + 1] = arr[j]; j--; }
        arr[j + 1] = v;
    }
}
__global__ void kUniqueCount(const int* __restrict__ arr, const int* __restrict__ offA,
                             int* __restrict__ ucnt) {
    int u = blockIdx.x * 256 + threadIdx.x;
    if (u >= NND) return;
    int s = offA[u], e = offA[u + 1], c = 0;
    for (int i = s; i < e; i++) c += (i == s) || (arr[i] != arr[i - 1]);
    ucnt[u] = c;
}
__global__ void kCompact(const int* __restrict__ arr, const int* __restrict__ offA,
                         const int* __restrict__ uoff, int* __restrict__ eU,
                         int* __restrict__ eV) {
    int u = blockIdx.x * 256 + threadIdx.x;
    if (u >= NND) return;
    int s = offA[u], e = offA[u + 1], o = uoff[u];
    for (int i = s; i < e; i++)
        if (i == s || arr[i] != arr[i - 1]) { eU[o] = u; eV[o] = arr[i]; o++; }
}

// ---------------- incidence CSR ----------------
__global__ void kIncCount(const int* __restrict__ eU, const int* __restrict__ eV,
                          const int* __restrict__ scal, int* __restrict__ icnt) {
    int e = blockIdx.x * 256 + threadIdx.x;
    if (e >= scal[0]) return;
    atomicAdd(&icnt[eU[e]], 1);
    atomicAdd(&icnt[eV[e]], 1);
}
__global__ void kIncScatter(const int* __restrict__ eU, const int* __restrict__ eV,
                            const int* __restrict__ scal, const int* __restrict__ ioff,
                            int* __restrict__ itmp, int* __restrict__ ilist) {
    int e = blockIdx.x * 256 + threadIdx.x;
    if (e >= scal[0]) return;
    int u = eU[e], v = eV[e];
    ilist[ioff[u] + atomicAdd(&itmp[u], 1)] = e;
    ilist[ioff[v] + atomicAdd(&itmp[v], 1)] = e;
}
__global__ void kDinv(const int* __restrict__ eU, const int* __restrict__ eV,
                      const int* __restrict__ icnt, const int* __restrict__ scal,
                      float* __restrict__ dinv) {
    int e = blockIdx.x * 256 + threadIdx.x;
    if (e >= scal[0]) return;
    dinv[e] = rsqrtf((float)(icnt[eU[e]] + icnt[eV[e]] - 1));
}

// ---------------- GEMM: h = (0.5*(x[u]+x[v])) @ W1 ----------------
// 256 threads / 64 edges per block. W1 (32KB) + xs (64x132 padded, 33.8KB) in
// LDS; each thread owns a 4-edge x 4-channel register tile (16 accs), so one
// W1 float4 LDS read feeds 16 FMAs. Serial k=0..127 per output -> bitwise
// identical to the naive dot product.
__global__ void kGemm(const float* __restrict__ x, const float* __restrict__ W1,
                      const int* __restrict__ eU, const int* __restrict__ eV,
                      const int* __restrict__ scal, float* __restrict__ h) {
    __shared__ float W1s[ICH][HIDC];
    __shared__ float xs[GEB][XS_PAD];
    int t = threadIdx.x;
    int E = scal[0];
    int e0 = blockIdx.x * GEB;
    if (e0 >= E) return;

    // stage W1: 2048 float4, 8 per thread
    {
        const float4* Wv = (const float4*)W1;
        float4* Ws = (float4*)&W1s[0][0];
        for (int i = t; i < ICH * HIDC / 4; i += 256) Ws[i] = Wv[i];
    }
    // stage xs: edge eb = t>>2, quarter q = t&3 covers channels [q*32, q*32+32)
    {
        int eb = t >> 2, q = t & 3;
        int e = e0 + eb;
        if (e < E) {
            int u = eU[e], v = eV[e];
            const float4* xu = (const float4*)(x + (size_t)u * ICH) + q * 8;
            const float4* xv = (const float4*)(x + (size_t)v * ICH) + q * 8;
            float* xd = &xs[eb][q * 32];
#pragma unroll
            for (int i = 0; i < 8; i++) {
                float4 a = xu[i], b = xv[i];
                xd[i * 4 + 0] = 0.5f * (a.x + b.x);
                xd[i * 4 + 1] = 0.5f * (a.y + b.y);
                xd[i * 4 + 2] = 0.5f * (a.z + b.z);
                xd[i * 4 + 3] = 0.5f * (a.w + b.w);
            }
        }
    }
    __syncthreads();

    int cg4 = (t & 15) * 4;   // channel quad
    int es = t >> 4;          // edge slot 0..15 -> edges es, es+16, es+32, es+48
    float a00=0,a01=0,a02=0,a03=0, a10=0,a11=0,a12=0,a13=0;
    float a20=0,a21=0,a22=0,a23=0, a30=0,a31=0,a32=0,a33=0;
#pragma unroll 4
    for (int k = 0; k < ICH; k++) {
        float4 wv = *(const float4*)&W1s[k][cg4];
        float x0 = xs[es][k], x1 = xs[es + 16][k];
        float x2 = xs[es + 32][k], x3 = xs[es + 48][k];
        a00 += x0 * wv.x; a01 += x0 * wv.y; a02 += x0 * wv.z; a03 += x0 * wv.w;
        a10 += x1 * wv.x; a11 += x1 * wv.y; a12 += x1 * wv.z; a13 += x1 * wv.w;
        a20 += x2 * wv.x; a21 += x2 * wv.y; a22 += x2 * wv.z; a23 += x2 * wv.w;
        a30 += x3 * wv.x; a31 += x3 * wv.y; a32 += x3 * wv.z; a33 += x3 * wv.w;
    }
    int e;
    e = e0 + es;
    if (e < E) *(float4*)&h[(size_t)e * HIDC + cg4] = make_float4(a00, a01, a02, a03);
    e = e0 + es + 16;
    if (e < E) *(float4*)&h[(size_t)e * HIDC + cg4] = make_float4(a10, a11, a12, a13);
    e = e0 + es + 32;
    if (e < E) *(float4*)&h[(size_t)e * HIDC + cg4] = make_float4(a20, a21, a22, a23);
    e = e0 + es + 48;
    if (e < E) *(float4*)&h[(size_t)e * HIDC + cg4] = make_float4(a30, a31, a32, a33);
}

// S[n][c] = sum over incident edges e: h[e][c]*dinv[e]  (deterministic gather)
__global__ void kSGather(const float* __restrict__ h, const float* __restrict__ dinv,
                         const int* __restrict__ ioff, const int* __restrict__ ilist,
                         float* __restrict__ S) {
    int n = blockIdx.x;
    int c = threadIdx.x;
    int s = ioff[n], e = ioff[n + 1];
    float acc = 0.f;
    for (int j = s; j < e; j++) {
        int ed = ilist[j];
        acc += h[(size_t)ed * HIDC + c] * dinv[ed];
    }
    S[(size_t)n * HIDC + c] = acc;
}
__global__ void kConv1(const float* __restrict__ h, const float* __restrict__ S,
                       const float* __restrict__ dinv, const int* __restrict__ eU,
                       const int* __restrict__ eV, const float* __restrict__ b1,
                       const int* __restrict__ scal, float* __restrict__ h2) {
    int idx = blockIdx.x * 256 + threadIdx.x;
    int e = idx >> 6;
    if (e >= scal[0]) return;
    int c = idx & 63;
    float a = dinv[e];
    h2[idx] = a * (S[(size_t)eU[e] * HIDC + c] + S[(size_t)eV[e] * HIDC + c]) -
              a * a * h[idx] + b1[c];
}

// ---------------- mean/var (deterministic two-level) ----------------
__global__ void kRed1(const float* __restrict__ h2, const int* __restrict__ scal,
                      const float* __restrict__ muvar, float* __restrict__ partial,
                      int pass) {
    int g = blockIdx.x, c = threadIdx.x;
    int E = scal[0];
    float m = pass ? muvar[c] : 0.f;
    float acc = 0.f;
    for (int e = g; e < E; e += 256) {
        float v = h2[(size_t)e * HIDC + c];
        if (pass) { float d = v - m; acc += d * d; }
        else acc += v;
    }
    partial[g * HIDC + c] = acc;
}
__global__ void kRed2(const float* __restrict__ partial, const int* __restrict__ scal,
                      float* __restrict__ muvar, int pass) {
    int c = threadIdx.x;
    float acc = 0.f;
    for (int g = 0; g < 256; g++) acc += partial[g * HIDC + c];
    muvar[pass * HIDC + c] = acc / (float)scal[0];
}
// fused batchnorm+relu+dot(W2): hn is never materialized (kZ merged in).
// Shuffle tree identical to the old kZ -> bitwise-identical z.
__global__ void kNormZ(const float* __restrict__ h2, const float* __restrict__ muvar,
                       const float* __restrict__ gamma1, const float* __restrict__ beta1,
                       const float* __restrict__ W2, const int* __restrict__ scal,
                       float* __restrict__ z) {
    int idx = blockIdx.x * 256 + threadIdx.x;
    int e = idx >> 6;
    if (e >= scal[0]) return;
    int c = idx & 63;
    float t = gamma1[c] * (h2[idx] - muvar[c]) * rsqrtf(muvar[HIDC + c] + 1e-5f) + beta1[c];
    t = t > 0.f ? t : 0.f;
    float p = t * W2[c];
#pragma unroll
    for (int o = 32; o > 0; o >>= 1) p += __shfl_down(p, o, 64);
    if (c == 0) z[e] = p;
}
__global__ void kS2(const float* __restrict__ z, const float* __restrict__ dinv,
                    const int* __restrict__ ioff, const int* __restrict__ ilist,
                    float* __restrict__ S2) {
    int n = blockIdx.x * 256 + threadIdx.x;
    if (n >= NND) return;
    float acc = 0.f;
    for (int j = ioff[n]; j < ioff[n + 1]; j++) {
        int e = ilist[j];
        acc += z[e] * dinv[e];
    }
    S2[n] = acc;
}
__global__ void kScore(const float* __restrict__ z, const float* __restrict__ S2,
                       const float* __restrict__ dinv, const int* __restrict__ eU,
                       const int* __restrict__ eV, const float* __restrict__ b2,
                       const int* __restrict__ scal, float* __restrict__ score,
                       u64* __restrict__ okey) {
    int e = blockIdx.x * 256 + threadIdx.x;
    if (e >= scal[0]) return;
    float a = dinv[e];
    float l = a * (S2[eU[e]] + S2[eV[e]]) - a * a * z[e] + b2[0];
    float s = 1.f / (1.f + expf(-l));
    score[e] = s;
    u32 b = __float_as_uint(s);
    b = (b >> 31) ? ~b : (b | 0x80000000u);
    okey[e] = (((u64)b) << 32) | (u32)(0xFFFFFFFFu - (u32)e);
}

// ---------------- radix select (k-th largest okey) ----------------
__global__ void kSelInit(const int* __restrict__ scal, int* __restrict__ krem,
                         u64* __restrict__ pref) {
    int E = scal[0];
    int k = E / 2;
    if (k > NND / 2) k = NND / 2;
    if (k < 1) k = 1;
    *krem = k;
    *pref = 0ULL;
}
// LDS-aggregated histogram: per-block 256-bin LDS hist, one global atomic
// per bin per block (kills same-address global-atomic serialization).
__global__ void kHist(const u64* __restrict__ okey, const int* __restrict__ scal,
                      int* __restrict__ hist, const u64* __restrict__ pref,
                      u64 maskHi, int shift) {
    __shared__ int sh[256];
    sh[threadIdx.x] = 0;
    __syncthreads();
    int E = scal[0];
    u64 p = *pref;
    for (int e = blockIdx.x * 256 + threadIdx.x; e < E; e += HIST_BLOCKS * 256) {
        u64 k = okey[e];
        if ((k & maskHi) == p)
            atomicAdd(&sh[(int)((k >> shift) & 255ULL)], 1);
    }
    __syncthreads();
    int v = sh[threadIdx.x];
    if (v) atomicAdd(&hist[threadIdx.x], v);
}
// consumes hist, then zeroes it for the next pass
__global__ void kSelPass(int* __restrict__ hist, u64* __restrict__ pref,
                         int* __restrict__ krem, int shift) {
    __shared__ int sh[256];
    sh[threadIdx.x] = hist[threadIdx.x];
    __syncthreads();
    hist[threadIdx.x] = 0;
    if (threadIdx.x == 0) {
        int kr = *krem;
        int cumAbove = 0;
        int b = 255;
        for (; b >= 0; b--) {
            int hcnt = sh[b];
            if (cumAbove + hcnt >= kr) break;
            cumAbove += hcnt;
        }
        if (b < 0) b = 0;
        *krem = kr - cumAbove;
        *pref |= ((u64)b) << shift;
    }
}

// ---------------- clustering ----------------
__global__ void kN2cInit(int* __restrict__ n2c) {
    int n = blockIdx.x * 256 + threadIdx.x;
    if (n < NND) n2c[n] = n;
}
__global__ void kMinKey(const u64* __restrict__ okey, const int* __restrict__ eV,
                        const int* __restrict__ scal, const u64* __restrict__ pref,
                        u64* __restrict__ minOkey) {
    int e = blockIdx.x * 256 + threadIdx.x;
    if (e >= scal[0]) return;
    u64 k = okey[e];
    if (k >= *pref) atomicMin(&minOkey[eV[e]], k);
}
__global__ void kN2cSet(const u64* __restrict__ okey, const int* __restrict__ eU,
                        const int* __restrict__ eV, const int* __restrict__ scal,
                        const u64* __restrict__ pref, const u64* __restrict__ minOkey,
                        int* __restrict__ n2c) {
    int e = blockIdx.x * 256 + threadIdx.x;
    if (e >= scal[0]) return;
    u64 k = okey[e];
    int v = eV[e];
    if (k >= *pref && k == minOkey[v]) n2c[v] = eU[e];
}
__global__ void kPresent(const int* __restrict__ n2c, int* __restrict__ present) {
    int n = blockIdx.x * 256 + threadIdx.x;
    if (n < NND) present[n2c[n]] = 1;
}
__global__ void kNi(const int* __restrict__ n2c, const int* __restrict__ o2n,
                    int* __restrict__ ni) {
    int n = blockIdx.x * 256 + threadIdx.x;
    if (n < NND) ni[n] = o2n[n2c[n]];
}

// ---------------- pooled features ----------------
__global__ void kCcnt(const int* __restrict__ ni, int* __restrict__ ccnt) {
    int n = blockIdx.x * 256 + threadIdx.x;
    if (n < NND) atomicAdd(&ccnt[ni[n]], 1);
}
__global__ void kXacc(const float* __restrict__ x, const int* __restrict__ ni,
                      float* __restrict__ dout) {
    int idx = blockIdx.x * 256 + threadIdx.x;
    if (idx >= NND * ICH) return;
    int n = idx >> 7, c = idx & 127;
    atomicAdd(&dout[(size_t)ni[n] * ICH + c], x[idx]);
}
__global__ void kXdiv(float* __restrict__ dout, const int* __restrict__ ccnt,
                      const int* __restrict__ scal) {
    int idx = blockIdx.x * 256 + threadIdx.x;
    int m = idx >> 7;
    if (m >= scal[2]) return;
    dout[idx] /= (float)ccnt[m];
}

// ---------------- pooled edges ----------------
__global__ void kCEcount(const int* __restrict__ ei, const int* __restrict__ ni,
                         int* __restrict__ ecnt2) {
    int i = blockIdx.x * 256 + threadIdx.x;
    if (i >= EUA) return;
    int a = ni[ei[i]], b = ni[ei[EUA + i]];
    if (a != b) atomicAdd(&ecnt2[a], 1);
}
__global__ void kCEscatter(const int* __restrict__ ei, const int* __restrict__ ni,
                           const int* __restrict__ eoff2, int* __restrict__ etmp2,
                           int* __restrict__ bkD) {
    int i = blockIdx.x * 256 + threadIdx.x;
    if (i >= EUA) return;
    int a = ni[ei[i]], b = ni[ei[EUA + i]];
    if (a != b) {
        int p = eoff2[a] + atomicAdd(&etmp2[a], 1);
        bkD[p] = b;
    }
}
// wave-parallel rank sort per bucket
__global__ void kRankSort(const int* __restrict__ in, int* __restrict__ out,
                          const int* __restrict__ offA, int* __restrict__ ucnt) {
    int a = blockIdx.x;
    int s = offA[a], e = offA[a + 1], len = e - s;
    for (int j = threadIdx.x; j < len; j += 64) {
        int v = in[s + j];
        int r = 0;
        for (int i = 0; i < len; i++) {
            int w = in[s + i];
            r += (w < v) || (w == v && i < j);
        }
        out[s + r] = v;
    }
    __syncthreads();
    int c = 0;
    for (int j = threadIdx.x; j < len; j += 64)
        c += (j == 0) || (out[s + j] != out[s + j - 1]);
#pragma unroll
    for (int o = 32; o > 0; o >>= 1) c += __shfl_down(c, o, 64);
    if (threadIdx.x == 0) ucnt[a] = c;
}
__global__ void kCEwrite(const int* __restrict__ bkD2, const int* __restrict__ offA,
                         const int* __restrict__ ueoff, const int* __restrict__ scal,
                         float* __restrict__ dout) {
    int a = blockIdx.x * 256 + threadIdx.x;
    if (a >= NND) return;
    int s = offA[a], e = offA[a + 1];
    int M = scal[2], Ep = scal[3];
    float* r0 = dout + (size_t)M * ICH;
    float* r1 = r0 + Ep;
    int o = ueoff[a];
    for (int i = s; i < e; i++)
        if (i == s || bkD2[i] != bkD2[i - 1]) {
            r0[o] = (float)a;
            r1[o] = (float)bkD2[i];
            o++;
        }
}

// ---------------- trailing outputs ----------------
__global__ void kBatchPool(const int* __restrict__ batch, const int* __restrict__ present,
                           const int* __restrict__ o2n, const int* __restrict__ scal,
                           float* __restrict__ dout) {
    int n = blockIdx.x * 256 + threadIdx.x;
    if (n >= NND) return;
    if (present[n]) {
        size_t base = (size_t)scal[2] * ICH + 2 * (size_t)scal[3];
        dout[base + o2n[n]] = (float)batch[n];
    }
}
__global__ void kScoresOut(const float* __restrict__ score, const int* __restrict__ scal,
                           float* __restrict__ dout) {
    int e = blockIdx.x * 256 + threadIdx.x;
    if (e >= scal[0]) return;
    size_t base = (size_t)scal[2] * ICH + 2 * (size_t)scal[3] + scal[2];
    dout[base + e] = score[e];
}
__global__ void kNiOut(const int* __restrict__ ni, const int* __restrict__ scal,
                       float* __restrict__ dout) {
    int n = blockIdx.x * 256 + threadIdx.x;
    if (n >= NND) return;
    size_t base = (size_t)scal[2] * ICH + 2 * (size_t)scal[3] + scal[2] + scal[0];
    dout[base + n] = (float)ni[n];
}

extern "C" void kernel_launch(void* const* d_in, const int* in_sizes, int n_in,
                              void* d_out, int out_size, void* d_ws, size_t ws_size,
                              hipStream_t stream) {
    (void)in_sizes; (void)n_in; (void)ws_size;
    const float* x = (const float*)d_in[0];
    const float* W1 = (const float*)d_in[1];
    const float* b1 = (const float*)d_in[2];
    const float* gamma1 = (const float*)d_in[3];
    const float* beta1 = (const float*)d_in[4];
    const float* W2 = (const float*)d_in[5];
    const float* b2 = (const float*)d_in[6];
    const int* ei = (const int*)d_in[7];
    const int* batch = (const int*)d_in[8];
    float* dout = (float*)d_out;

    char* w = (char*)d_ws;
    size_t off = 0;
    auto carve = [&](size_t bytes) -> void* {
        off = (off + 255) & ~(size_t)255;
        void* p = w + off;
        off += bytes;
        return p;
    };
    // ---- contiguous zero-init region (ONE memset covers all of these) ----
    char* zero0 = w;
    int* cnt = (int*)carve(NND * 4);
    int* tmp = (int*)carve(NND * 4);
    int* icnt = (int*)carve(NND * 4);
    int* itmp = (int*)carve(NND * 4);
    int* present = (int*)carve(NND * 4);
    int* ccnt = (int*)carve(NND * 4);
    int* ecnt2 = (int*)carve(NND * 4);
    int* etmp2 = (int*)carve(NND * 4);
    int* scal = (int*)carve(16 * 4);
    int* hist = (int*)carve(256 * 4);
    size_t zeroBytes = off;
    // ---- rest ----
    int* offA = (int*)carve((NND + 2) * 4);
    int* ucnt = (int*)carve(NND * 4);
    int* uoff = (int*)carve((NND + 2) * 4);
    int* ioff = (int*)carve((NND + 2) * 4);
    int* bsums = (int*)carve((NSCAN_B + 2) * 4);
    int* n2c = (int*)carve(NND * 4);
    int* o2n = (int*)carve((NND + 2) * 4);
    int* niArr = (int*)carve(NND * 4);
    int* eoff2 = (int*)carve((NND + 2) * 4);
    int* uecnt = (int*)carve(NND * 4);
    int* ueoff = (int*)carve((NND + 2) * 4);
    int* bucketV = (int*)carve(EUA * 4);
    int* eU = (int*)carve(EFE * 4);
    int* eV = (int*)carve(EFE * 4);
    int* ilist = (int*)carve(2 * EFE * 4);
    int* bkD = (int*)carve(EUA * 4);
    int* bkD2 = (int*)carve(EUA * 4);
    u64* okey = (u64*)carve(EFE * 8);
    u64* minOkey = (u64*)carve(NND * 8);
    u64* dpref = (u64*)carve(8);
    float* dinv = (float*)carve(EFE * 4);
    float* h = (float*)carve((size_t)EFE * HIDC * 4);
    float* h2 = (float*)carve((size_t)EFE * HIDC * 4);
    float* Snode = (float*)carve((size_t)NND * HIDC * 4);
    float* partial = (float*)carve(256 * HIDC * 4);
    float* muvar = (float*)carve(128 * 4);
    float* zArr = (float*)carve(EFE * 4);
    float* S2 = (float*)carve(NND * 4);
    float* score = (float*)carve(EFE * 4);

    auto scan = [&](const int* in, int* outp, int* totalDst) {
        scan1<<<NSCAN_B, SCAN_BS, 0, stream>>>(in, outp, bsums, NND);
        scan2<<<1, 128, 0, stream>>>(bsums, NSCAN_B);
        scan3<<<NSCAN_B, SCAN_BS, 0, stream>>>(outp, bsums, NND, NSCAN_B, totalDst);
    };

    // zero state: one memset for all zero-init scratch, plus minOkey=0xFF and d_out=0
    hipMemsetAsync(zero0, 0, zeroBytes, stream);
    hipMemsetAsync(minOkey, 0xFF, NND * 8, stream);
    hipMemsetAsync(d_out, 0, (size_t)out_size * 4, stream);

    // clean edge list (sorted by (u,v), deduped)
    kFilterCount<<<NB_EU, 256, 0, stream>>>(ei, cnt);
    scan(cnt, offA, scal + 15);
    kFilterScatter<<<NB_EU, 256, 0, stream>>>(ei, offA, tmp, bucketV);
    kSortSeg<<<NB_N, 256, 0, stream>>>(bucketV, offA);
    kUniqueCount<<<NB_N, 256, 0, stream>>>(bucketV, offA, ucnt);
    scan(ucnt, uoff, scal + 0);  // scal[0] = E
    kCompact<<<NB_N, 256, 0, stream>>>(bucketV, offA, uoff, eU, eV);

    // incidence CSR (sorted -> deterministic gathers)
    kIncCount<<<NB_EF, 256, 0, stream>>>(eU, eV, scal, icnt);
    scan(icnt, ioff, scal + 15);
    kIncScatter<<<NB_EF, 256, 0, stream>>>(eU, eV, scal, ioff, itmp, ilist);
    kSortSeg<<<NB_N, 256, 0, stream>>>(ilist, ioff);
    kDinv<<<NB_EF, 256, 0, stream>>>(eU, eV, icnt, scal, dinv);

    // conv1
    kGemm<<<(EFE + GEB - 1) / GEB, 256, 0, stream>>>(x, W1, eU, eV, scal, h);
    kSGather<<<NND, HIDC, 0, stream>>>(h, dinv, ioff, ilist, Snode);
    kConv1<<<NB_E64, 256, 0, stream>>>(h, Snode, dinv, eU, eV, b1, scal, h2);

    // batch-norm stats + fused norm/relu/dot(W2)
    kRed1<<<256, HIDC, 0, stream>>>(h2, scal, muvar, partial, 0);
    kRed2<<<1, HIDC, 0, stream>>>(partial, scal, muvar, 0);
    kRed1<<<256, HIDC, 0, stream>>>(h2, scal, muvar, partial, 1);
    kRed2<<<1, HIDC, 0, stream>>>(partial, scal, muvar, 1);
    kNormZ<<<NB_E64, 256, 0, stream>>>(h2, muvar, gamma1, beta1, W2, scal, zArr);

    // conv2 -> scores + sortable keys
    kS2<<<NB_N, 256, 0, stream>>>(zArr, dinv, ioff, ilist, S2);
    kScore<<<NB_EF, 256, 0, stream>>>(zArr, S2, dinv, eU, eV, b2, scal, score, okey);

    // exact k-th largest via 8x8-bit radix select
    kSelInit<<<1, 1, 0, stream>>>(scal, scal + 1, dpref);
    for (int p = 0; p < 8; p++) {
        int shift = 56 - 8 * p;
        u64 maskHi = (p == 0) ? 0ULL : ((~0ULL) << (shift + 8));
        kHist<<<HIST_BLOCKS, 256, 0, stream>>>(okey, scal, hist, dpref, maskHi, shift);
        kSelPass<<<1, 256, 0, stream>>>(hist, dpref, scal + 1, shift);
    }

    // cluster: per-dst last-in-topk-order edge
    kMinKey<<<NB_EF, 256, 0, stream>>>(okey, eV, scal, dpref, minOkey);
    kN2cInit<<<NB_N, 256, 0, stream>>>(n2c);
    kN2cSet<<<NB_EF, 256, 0, stream>>>(okey, eU, eV, scal, dpref, minOkey, n2c);
    kPresent<<<NB_N, 256, 0, stream>>>(n2c, present);
    scan(present, o2n, scal + 2);  // scal[2] = M
    kNi<<<NB_N, 256, 0, stream>>>(n2c, o2n, niArr);

    // pooled features (x_pool lives at d_out offset 0; d_out zeroed upfront)
    kCcnt<<<NB_N, 256, 0, stream>>>(niArr, ccnt);
    kXacc<<<NB_X, 256, 0, stream>>>(x, niArr, dout);
    kXdiv<<<NB_X, 256, 0, stream>>>(dout, ccnt, scal);

    // pooled edges
    kCEcount<<<NB_EU, 256, 0, stream>>>(ei, niArr, ecnt2);
    scan(ecnt2, eoff2, scal + 4);
    kCEscatter<<<NB_EU, 256, 0, stream>>>(ei, niArr, eoff2, etmp2, bkD);
    kRankSort<<<NND, 64, 0, stream>>>(bkD, bkD2, eoff2, uecnt);
    scan(uecnt, ueoff, scal + 3);  // scal[3] = Ep
    kCEwrite<<<NB_N, 256, 0, stream>>>(bkD2, eoff2, ueoff, scal, dout);

    // batch_pool, scores, ni
    kBatchPool<<<NB_N, 256, 0, stream>>>(batch, present, o2n, scal, dout);
    kScoresOut<<<NB_EF, 256, 0, stream>>>(score, scal, dout);
    kNiOut<<<NB_N, 256, 0, stream>>>(niArr, scal, dout);
}

// Round 4
// 524.986 us; speedup vs baseline: 3.0834x; 1.1375x over previous
//
#include <hip/hip_runtime.h>
#include <stdint.h>

typedef unsigned long long u64;
typedef unsigned int u32;

#define NND 20000      // nodes
#define EUA 160000     // directed input edges (2 * E_UND)
#define EFE 80000      // max clean (undirected, deduped) edges
#define ICH 128
#define HIDC 64
#define SCAN_BS 256
#define NB_N ((NND + 255) / 256)
#define NB_EU ((EUA + 255) / 256)
#define NB_EF ((EFE + 255) / 256)
#define NB_E64 ((EFE * HIDC + 255) / 256)
#define NB_X ((NND * ICH + 255) / 256)
#define NSCAN_B ((NND + SCAN_BS - 1) / SCAN_BS)
#define HIST_BLOCKS 128
#define GEB 64         // edges per gemm block
#define XS_PAD 132     // xs leading-dim pad (bank-conflict-free for 4-edge groups)
#define NCHAIN 4096    // mean/var reduction chains (was 256: 1 wave/CU, latency-bound)

// scal slots: 0=E, 1=kRem, 2=M, 3=Ep, 4=Ekept, 15=dummy

// ---------------- scan (exclusive, n = NND fixed) ----------------
__global__ void scan1(const int* __restrict__ in, int* __restrict__ out,
                      int* __restrict__ bsums, int n) {
    __shared__ int sh[SCAN_BS];
    int tid = threadIdx.x;
    int i = blockIdx.x * SCAN_BS + tid;
    int v = (i < n) ? in[i] : 0;
    sh[tid] = v;
    __syncthreads();
    for (int o = 1; o < SCAN_BS; o <<= 1) {
        int t = (tid >= o) ? sh[tid - o] : 0;
        __syncthreads();
        sh[tid] += t;
        __syncthreads();
    }
    if (i < n) out[i] = sh[tid] - v;  // exclusive
    if (tid == SCAN_BS - 1) bsums[blockIdx.x] = sh[tid];
}
__global__ void scan2(int* __restrict__ bsums, int nb) {
    __shared__ int sh[160];
    int tid = threadIdx.x;
    if (tid < nb) sh[tid] = bsums[tid];
    __syncthreads();
    if (tid == 0) {
        int acc = 0;
        for (int i = 0; i < nb; i++) { int t = sh[i]; sh[i] = acc; acc += t; }
        sh[nb] = acc;
    }
    __syncthreads();
    if (tid <= nb) bsums[tid] = sh[tid];
}
__global__ void scan3(int* __restrict__ out, const int* __restrict__ bsums,
                      int n, int nb, int* __restrict__ totalDst) {
    int i = blockIdx.x * SCAN_BS + threadIdx.x;
    if (i < n) out[i] += bsums[blockIdx.x];
    if (i == 0) {
        int tot = bsums[nb];
        out[n] = tot;
        *totalDst = tot;
    }
}

// ---------------- clean edge build ----------------
__global__ void kFilterCount(const int* __restrict__ ei, int* __restrict__ cnt) {
    int i = blockIdx.x * 256 + threadIdx.x;
    if (i >= EUA) return;
    int s = ei[i], d = ei[EUA + i];
    if (s < d) atomicAdd(&cnt[s], 1);
}
__global__ void kFilterScatter(const int* __restrict__ ei, const int* __restrict__ offA,
                               int* __restrict__ tmp, int* __restrict__ bucketV) {
    int i = blockIdx.x * 256 + threadIdx.x;
    if (i >= EUA) return;
    int s = ei[i], d = ei[EUA + i];
    if (s < d) {
        int p = offA[s] + atomicAdd(&tmp[s], 1);
        bucketV[p] = d;
    }
}
// insertion sort each segment (small buckets)
__global__ void kSortSeg(int* __restrict__ arr, const int* __restrict__ offA) {
    int u = blockIdx.x * 256 + threadIdx.x;
    if (u >= NND) return;
    int s = offA[u], e = offA[u + 1];
    for (int i = s + 1; i < e; i++) {
        int v = arr[i];
        int j = i - 1;
        while (j >= s && arr[j] > v) { arr[j + 1] = arr[j]; j--; }
        arr[j + 1] = v;
    }
}
__global__ void kUniqueCount(const int* __restrict__ arr, const int* __restrict__ offA,
                             int* __restrict__ ucnt) {
    int u = blockIdx.x * 256 + threadIdx.x;
    if (u >= NND) return;
    int s = offA[u], e = offA[u + 1], c = 0;
    for (int i = s; i < e; i++) c += (i == s) || (arr[i] != arr[i - 1]);
    ucnt[u] = c;
}
__global__ void kCompact(const int* __restrict__ arr, const int* __restrict__ offA,
                         const int* __restrict__ uoff, int* __restrict__ eU,
                         int* __restrict__ eV) {
    int u = blockIdx.x * 256 + threadIdx.x;
    if (u >= NND) return;
    int s = offA[u], e = offA[u + 1], o = uoff[u];
    for (int i = s; i < e; i++)
        if (i == s || arr[i] != arr[i - 1]) { eU[o] = u; eV[o] = arr[i]; o++; }
}

// ---------------- incidence CSR ----------------
__global__ void kIncCount(const int* __restrict__ eU, const int* __restrict__ eV,
                          const int* __restrict__ scal, int* __restrict__ icnt) {
    int e = blockIdx.x * 256 + threadIdx.x;
    if (e >= scal[0]) return;
    atomicAdd(&icnt[eU[e]], 1);
    atomicAdd(&icnt[eV[e]], 1);
}
__global__ void kIncScatter(const int* __restrict__ eU, const int* __restrict__ eV,
                            const int* __restrict__ scal, const int* __restrict__ ioff,
                            int* __restrict__ itmp, int* __restrict__ ilist) {
    int e = blockIdx.x * 256 + threadIdx.x;
    if (e >= scal[0]) return;
    int u = eU[e], v = eV[e];
    ilist[ioff[u] + atomicAdd(&itmp[u], 1)] = e;
    ilist[ioff[v] + atomicAdd(&itmp[v], 1)] = e;
}
__global__ void kDinv(const int* __restrict__ eU, const int* __restrict__ eV,
                      const int* __restrict__ icnt, const int* __restrict__ scal,
                      float* __restrict__ dinv) {
    int e = blockIdx.x * 256 + threadIdx.x;
    if (e >= scal[0]) return;
    dinv[e] = rsqrtf((float)(icnt[eU[e]] + icnt[eV[e]] - 1));
}

// ---------------- GEMM: h = (0.5*(x[u]+x[v])) @ W1 ----------------
// 256 threads / 64 edges per block. W1 (32KB) + xs (64x132 padded, 33.8KB) in
// LDS; each thread owns a 4-edge x 4-channel register tile (16 accs). Serial
// k=0..127 per output -> bitwise identical to the naive dot product.
__global__ void kGemm(const float* __restrict__ x, const float* __restrict__ W1,
                      const int* __restrict__ eU, const int* __restrict__ eV,
                      const int* __restrict__ scal, float* __restrict__ h) {
    __shared__ float W1s[ICH][HIDC];
    __shared__ float xs[GEB][XS_PAD];
    int t = threadIdx.x;
    int E = scal[0];
    int e0 = blockIdx.x * GEB;
    if (e0 >= E) return;

    // stage W1: 2048 float4, 8 per thread
    {
        const float4* Wv = (const float4*)W1;
        float4* Ws = (float4*)&W1s[0][0];
        for (int i = t; i < ICH * HIDC / 4; i += 256) Ws[i] = Wv[i];
    }
    // stage xs: edge eb = t>>2, quarter q = t&3 covers channels [q*32, q*32+32)
    {
        int eb = t >> 2, q = t & 3;
        int e = e0 + eb;
        if (e < E) {
            int u = eU[e], v = eV[e];
            const float4* xu = (const float4*)(x + (size_t)u * ICH) + q * 8;
            const float4* xv = (const float4*)(x + (size_t)v * ICH) + q * 8;
            float* xd = &xs[eb][q * 32];
#pragma unroll
            for (int i = 0; i < 8; i++) {
                float4 a = xu[i], b = xv[i];
                xd[i * 4 + 0] = 0.5f * (a.x + b.x);
                xd[i * 4 + 1] = 0.5f * (a.y + b.y);
                xd[i * 4 + 2] = 0.5f * (a.z + b.z);
                xd[i * 4 + 3] = 0.5f * (a.w + b.w);
            }
        }
    }
    __syncthreads();

    int cg4 = (t & 15) * 4;   // channel quad
    int es = t >> 4;          // edge slot 0..15 -> edges es, es+16, es+32, es+48
    float a00=0,a01=0,a02=0,a03=0, a10=0,a11=0,a12=0,a13=0;
    float a20=0,a21=0,a22=0,a23=0, a30=0,a31=0,a32=0,a33=0;
#pragma unroll 4
    for (int k = 0; k < ICH; k++) {
        float4 wv = *(const float4*)&W1s[k][cg4];
        float x0 = xs[es][k], x1 = xs[es + 16][k];
        float x2 = xs[es + 32][k], x3 = xs[es + 48][k];
        a00 += x0 * wv.x; a01 += x0 * wv.y; a02 += x0 * wv.z; a03 += x0 * wv.w;
        a10 += x1 * wv.x; a11 += x1 * wv.y; a12 += x1 * wv.z; a13 += x1 * wv.w;
        a20 += x2 * wv.x; a21 += x2 * wv.y; a22 += x2 * wv.z; a23 += x2 * wv.w;
        a30 += x3 * wv.x; a31 += x3 * wv.y; a32 += x3 * wv.z; a33 += x3 * wv.w;
    }
    int e;
    e = e0 + es;
    if (e < E) *(float4*)&h[(size_t)e * HIDC + cg4] = make_float4(a00, a01, a02, a03);
    e = e0 + es + 16;
    if (e < E) *(float4*)&h[(size_t)e * HIDC + cg4] = make_float4(a10, a11, a12, a13);
    e = e0 + es + 32;
    if (e < E) *(float4*)&h[(size_t)e * HIDC + cg4] = make_float4(a20, a21, a22, a23);
    e = e0 + es + 48;
    if (e < E) *(float4*)&h[(size_t)e * HIDC + cg4] = make_float4(a30, a31, a32, a33);
}

// S[n][c] = sum over incident edges e: h[e][c]*dinv[e]  (deterministic gather)
__global__ void kSGather(const float* __restrict__ h, const float* __restrict__ dinv,
                         const int* __restrict__ ioff, const int* __restrict__ ilist,
                         float* __restrict__ S) {
    int n = blockIdx.x;
    int c = threadIdx.x;
    int s = ioff[n], e = ioff[n + 1];
    float acc = 0.f;
    for (int j = s; j < e; j++) {
        int ed = ilist[j];
        acc += h[(size_t)ed * HIDC + c] * dinv[ed];
    }
    S[(size_t)n * HIDC + c] = acc;
}
__global__ void kConv1(const float* __restrict__ h, const float* __restrict__ S,
                       const float* __restrict__ dinv, const int* __restrict__ eU,
                       const int* __restrict__ eV, const float* __restrict__ b1,
                       const int* __restrict__ scal, float* __restrict__ h2) {
    int idx = blockIdx.x * 256 + threadIdx.x;
    int e = idx >> 6;
    if (e >= scal[0]) return;
    int c = idx & 63;
    float a = dinv[e];
    h2[idx] = a * (S[(size_t)eU[e] * HIDC + c] + S[(size_t)eV[e] * HIDC + c]) -
              a * a * h[idx] + b1[c];
}

// ---------------- mean/var (deterministic, 4096-chain tree) ----------------
// grid NCHAIN/4 x 256: thread (g,c) sums e = g, g+NCHAIN, ... (chain ~20,
// independent loads -> pipelined; 16 waves/CU vs old 1 wave/CU).
__global__ void kRed1(const float* __restrict__ h2, const int* __restrict__ scal,
                      const float* __restrict__ muvar, float* __restrict__ partial,
                      int pass) {
    int t = threadIdx.x;
    int g = blockIdx.x * 4 + (t >> 6);
    int c = t & 63;
    int E = scal[0];
    float m = pass ? muvar[c] : 0.f;
    float acc = 0.f;
    for (int e = g; e < E; e += NCHAIN) {
        float v = h2[(size_t)e * HIDC + c];
        if (pass) { float d = v - m; acc += d * d; }
        else acc += v;
    }
    partial[g * HIDC + c] = acc;
}
// one block of 256: quarter q sums 1024 partials/channel, then fixed-order
// combine q0..q3 (deterministic across replays).
__global__ void kRed2(const float* __restrict__ partial, const int* __restrict__ scal,
                      float* __restrict__ muvar, int pass) {
    __shared__ float sh[4][HIDC];
    int t = threadIdx.x;
    int q = t >> 6, c = t & 63;
    float acc = 0.f;
    int g0 = q * (NCHAIN / 4);
    for (int g = g0; g < g0 + NCHAIN / 4; g++) acc += partial[g * HIDC + c];
    sh[q][c] = acc;
    __syncthreads();
    if (q == 0) {
        float s = ((sh[0][c] + sh[1][c]) + sh[2][c]) + sh[3][c];
        muvar[pass * HIDC + c] = s / (float)scal[0];
    }
}
// fused batchnorm+relu+dot(W2): hn never materialized.
__global__ void kNormZ(const float* __restrict__ h2, const float* __restrict__ muvar,
                       const float* __restrict__ gamma1, const float* __restrict__ beta1,
                       const float* __restrict__ W2, const int* __restrict__ scal,
                       float* __restrict__ z) {
    int idx = blockIdx.x * 256 + threadIdx.x;
    int e = idx >> 6;
    if (e >= scal[0]) return;
    int c = idx & 63;
    float t = gamma1[c] * (h2[idx] - muvar[c]) * rsqrtf(muvar[HIDC + c] + 1e-5f) + beta1[c];
    t = t > 0.f ? t : 0.f;
    float p = t * W2[c];
#pragma unroll
    for (int o = 32; o > 0; o >>= 1) p += __shfl_down(p, o, 64);
    if (c == 0) z[e] = p;
}
__global__ void kS2(const float* __restrict__ z, const float* __restrict__ dinv,
                    const int* __restrict__ ioff, const int* __restrict__ ilist,
                    float* __restrict__ S2) {
    int n = blockIdx.x * 256 + threadIdx.x;
    if (n >= NND) return;
    float acc = 0.f;
    for (int j = ioff[n]; j < ioff[n + 1]; j++) {
        int e = ilist[j];
        acc += z[e] * dinv[e];
    }
    S2[n] = acc;
}
__global__ void kScore(const float* __restrict__ z, const float* __restrict__ S2,
                       const float* __restrict__ dinv, const int* __restrict__ eU,
                       const int* __restrict__ eV, const float* __restrict__ b2,
                       const int* __restrict__ scal, float* __restrict__ score,
                       u64* __restrict__ okey) {
    int e = blockIdx.x * 256 + threadIdx.x;
    if (e >= scal[0]) return;
    float a = dinv[e];
    float l = a * (S2[eU[e]] + S2[eV[e]]) - a * a * z[e] + b2[0];
    float s = 1.f / (1.f + expf(-l));
    score[e] = s;
    u32 b = __float_as_uint(s);
    b = (b >> 31) ? ~b : (b | 0x80000000u);
    okey[e] = (((u64)b) << 32) | (u32)(0xFFFFFFFFu - (u32)e);
}

// ---------------- radix select (k-th largest okey) ----------------
__global__ void kSelInit(const int* __restrict__ scal, int* __restrict__ krem,
                         u64* __restrict__ pref) {
    int E = scal[0];
    int k = E / 2;
    if (k > NND / 2) k = NND / 2;
    if (k < 1) k = 1;
    *krem = k;
    *pref = 0ULL;
}
// LDS-aggregated histogram (kills same-address global-atomic serialization).
__global__ void kHist(const u64* __restrict__ okey, const int* __restrict__ scal,
                      int* __restrict__ hist, const u64* __restrict__ pref,
                      u64 maskHi, int shift) {
    __shared__ int sh[256];
    sh[threadIdx.x] = 0;
    __syncthreads();
    int E = scal[0];
    u64 p = *pref;
    for (int e = blockIdx.x * 256 + threadIdx.x; e < E; e += HIST_BLOCKS * 256) {
        u64 k = okey[e];
        if ((k & maskHi) == p)
            atomicAdd(&sh[(int)((k >> shift) & 255ULL)], 1);
    }
    __syncthreads();
    int v = sh[threadIdx.x];
    if (v) atomicAdd(&hist[threadIdx.x], v);
}
// consumes hist, then zeroes it for the next pass
__global__ void kSelPass(int* __restrict__ hist, u64* __restrict__ pref,
                         int* __restrict__ krem, int shift) {
    __shared__ int sh[256];
    sh[threadIdx.x] = hist[threadIdx.x];
    __syncthreads();
    hist[threadIdx.x] = 0;
    if (threadIdx.x == 0) {
        int kr = *krem;
        int cumAbove = 0;
        int b = 255;
        for (; b >= 0; b--) {
            int hcnt = sh[b];
            if (cumAbove + hcnt >= kr) break;
            cumAbove += hcnt;
        }
        if (b < 0) b = 0;
        *krem = kr - cumAbove;
        *pref |= ((u64)b) << shift;
    }
}

// ---------------- clustering ----------------
__global__ void kN2cInit(int* __restrict__ n2c) {
    int n = blockIdx.x * 256 + threadIdx.x;
    if (n < NND) n2c[n] = n;
}
__global__ void kMinKey(const u64* __restrict__ okey, const int* __restrict__ eV,
                        const int* __restrict__ scal, const u64* __restrict__ pref,
                        u64* __restrict__ minOkey) {
    int e = blockIdx.x * 256 + threadIdx.x;
    if (e >= scal[0]) return;
    u64 k = okey[e];
    if (k >= *pref) atomicMin(&minOkey[eV[e]], k);
}
__global__ void kN2cSet(const u64* __restrict__ okey, const int* __restrict__ eU,
                        const int* __restrict__ eV, const int* __restrict__ scal,
                        const u64* __restrict__ pref, const u64* __restrict__ minOkey,
                        int* __restrict__ n2c) {
    int e = blockIdx.x * 256 + threadIdx.x;
    if (e >= scal[0]) return;
    u64 k = okey[e];
    int v = eV[e];
    if (k >= *pref && k == minOkey[v]) n2c[v] = eU[e];
}
__global__ void kPresent(const int* __restrict__ n2c, int* __restrict__ present) {
    int n = blockIdx.x * 256 + threadIdx.x;
    if (n < NND) present[n2c[n]] = 1;
}
__global__ void kNi(const int* __restrict__ n2c, const int* __restrict__ o2n,
                    int* __restrict__ ni) {
    int n = blockIdx.x * 256 + threadIdx.x;
    if (n < NND) ni[n] = o2n[n2c[n]];
}

// ---------------- pooled features ----------------
__global__ void kCcnt(const int* __restrict__ ni, int* __restrict__ ccnt) {
    int n = blockIdx.x * 256 + threadIdx.x;
    if (n < NND) atomicAdd(&ccnt[ni[n]], 1);
}
__global__ void kXacc(const float* __restrict__ x, const int* __restrict__ ni,
                      float* __restrict__ dout) {
    int idx = blockIdx.x * 256 + threadIdx.x;
    if (idx >= NND * ICH) return;
    int n = idx >> 7, c = idx & 127;
    atomicAdd(&dout[(size_t)ni[n] * ICH + c], x[idx]);
}
__global__ void kXdiv(float* __restrict__ dout, const int* __restrict__ ccnt,
                      const int* __restrict__ scal) {
    int idx = blockIdx.x * 256 + threadIdx.x;
    int m = idx >> 7;
    if (m >= scal[2]) return;
    dout[idx] /= (float)ccnt[m];
}

// ---------------- pooled edges ----------------
__global__ void kCEcount(const int* __restrict__ ei, const int* __restrict__ ni,
                         int* __restrict__ ecnt2) {
    int i = blockIdx.x * 256 + threadIdx.x;
    if (i >= EUA) return;
    int a = ni[ei[i]], b = ni[ei[EUA + i]];
    if (a != b) atomicAdd(&ecnt2[a], 1);
}
__global__ void kCEscatter(const int* __restrict__ ei, const int* __restrict__ ni,
                           const int* __restrict__ eoff2, int* __restrict__ etmp2,
                           int* __restrict__ bkD) {
    int i = blockIdx.x * 256 + threadIdx.x;
    if (i >= EUA) return;
    int a = ni[ei[i]], b = ni[ei[EUA + i]];
    if (a != b) {
        int p = eoff2[a] + atomicAdd(&etmp2[a], 1);
        bkD[p] = b;
    }
}
// wave-parallel rank sort per bucket
__global__ void kRankSort(const int* __restrict__ in, int* __restrict__ out,
                          const int* __restrict__ offA, int* __restrict__ ucnt) {
    int a = blockIdx.x;
    int s = offA[a], e = offA[a + 1], len = e - s;
    for (int j = threadIdx.x; j < len; j += 64) {
        int v = in[s + j];
        int r = 0;
        for (int i = 0; i < len; i++) {
            int w = in[s + i];
            r += (w < v) || (w == v && i < j);
        }
        out[s + r] = v;
    }
    __syncthreads();
    int c = 0;
    for (int j = threadIdx.x; j < len; j += 64)
        c += (j == 0) || (out[s + j] != out[s + j - 1]);
#pragma unroll
    for (int o = 32; o > 0; o >>= 1) c += __shfl_down(c, o, 64);
    if (threadIdx.x == 0) ucnt[a] = c;
}
__global__ void kCEwrite(const int* __restrict__ bkD2, const int* __restrict__ offA,
                         const int* __restrict__ ueoff, const int* __restrict__ scal,
                         float* __restrict__ dout) {
    int a = blockIdx.x * 256 + threadIdx.x;
    if (a >= NND) return;
    int s = offA[a], e = offA[a + 1];
    int M = scal[2], Ep = scal[3];
    float* r0 = dout + (size_t)M * ICH;
    float* r1 = r0 + Ep;
    int o = ueoff[a];
    for (int i = s; i < e; i++)
        if (i == s || bkD2[i] != bkD2[i - 1]) {
            r0[o] = (float)a;
            r1[o] = (float)bkD2[i];
            o++;
        }
}

// ---------------- trailing outputs ----------------
__global__ void kBatchPool(const int* __restrict__ batch, const int* __restrict__ present,
                           const int* __restrict__ o2n, const int* __restrict__ scal,
                           float* __restrict__ dout) {
    int n = blockIdx.x * 256 + threadIdx.x;
    if (n >= NND) return;
    if (present[n]) {
        size_t base = (size_t)scal[2] * ICH + 2 * (size_t)scal[3];
        dout[base + o2n[n]] = (float)batch[n];
    }
}
__global__ void kScoresOut(const float* __restrict__ score, const int* __restrict__ scal,
                           float* __restrict__ dout) {
    int e = blockIdx.x * 256 + threadIdx.x;
    if (e >= scal[0]) return;
    size_t base = (size_t)scal[2] * ICH + 2 * (size_t)scal[3] + scal[2];
    dout[base + e] = score[e];
}
__global__ void kNiOut(const int* __restrict__ ni, const int* __restrict__ scal,
                       float* __restrict__ dout) {
    int n = blockIdx.x * 256 + threadIdx.x;
    if (n >= NND) return;
    size_t base = (size_t)scal[2] * ICH + 2 * (size_t)scal[3] + scal[2] + scal[0];
    dout[base + n] = (float)ni[n];
}

extern "C" void kernel_launch(void* const* d_in, const int* in_sizes, int n_in,
                              void* d_out, int out_size, void* d_ws, size_t ws_size,
                              hipStream_t stream) {
    (void)in_sizes; (void)n_in; (void)ws_size;
    const float* x = (const float*)d_in[0];
    const float* W1 = (const float*)d_in[1];
    const float* b1 = (const float*)d_in[2];
    const float* gamma1 = (const float*)d_in[3];
    const float* beta1 = (const float*)d_in[4];
    const float* W2 = (const float*)d_in[5];
    const float* b2 = (const float*)d_in[6];
    const int* ei = (const int*)d_in[7];
    const int* batch = (const int*)d_in[8];
    float* dout = (float*)d_out;

    char* w = (char*)d_ws;
    size_t off = 0;
    auto carve = [&](size_t bytes) -> void* {
        off = (off + 255) & ~(size_t)255;
        void* p = w + off;
        off += bytes;
        return p;
    };
    // ---- contiguous zero-init region (ONE memset covers all of these) ----
    char* zero0 = w;
    int* cnt = (int*)carve(NND * 4);
    int* tmp = (int*)carve(NND * 4);
    int* icnt = (int*)carve(NND * 4);
    int* itmp = (int*)carve(NND * 4);
    int* present = (int*)carve(NND * 4);
    int* ccnt = (int*)carve(NND * 4);
    int* ecnt2 = (int*)carve(NND * 4);
    int* etmp2 = (int*)carve(NND * 4);
    int* scal = (int*)carve(16 * 4);
    int* hist = (int*)carve(256 * 4);
    size_t zeroBytes = off;
    // ---- rest ----
    int* offA = (int*)carve((NND + 2) * 4);
    int* ucnt = (int*)carve(NND * 4);
    int* uoff = (int*)carve((NND + 2) * 4);
    int* ioff = (int*)carve((NND + 2) * 4);
    int* bsums = (int*)carve((NSCAN_B + 2) * 4);
    int* n2c = (int*)carve(NND * 4);
    int* o2n = (int*)carve((NND + 2) * 4);
    int* niArr = (int*)carve(NND * 4);
    int* eoff2 = (int*)carve((NND + 2) * 4);
    int* uecnt = (int*)carve(NND * 4);
    int* ueoff = (int*)carve((NND + 2) * 4);
    int* bucketV = (int*)carve(EUA * 4);
    int* eU = (int*)carve(EFE * 4);
    int* eV = (int*)carve(EFE * 4);
    int* ilist = (int*)carve(2 * EFE * 4);
    int* bkD = (int*)carve(EUA * 4);
    int* bkD2 = (int*)carve(EUA * 4);
    u64* okey = (u64*)carve(EFE * 8);
    u64* minOkey = (u64*)carve(NND * 8);
    u64* dpref = (u64*)carve(8);
    float* dinv = (float*)carve(EFE * 4);
    float* h = (float*)carve((size_t)EFE * HIDC * 4);
    float* h2 = (float*)carve((size_t)EFE * HIDC * 4);
    float* Snode = (float*)carve((size_t)NND * HIDC * 4);
    float* partial = (float*)carve((size_t)NCHAIN * HIDC * 4);
    float* muvar = (float*)carve(128 * 4);
    float* zArr = (float*)carve(EFE * 4);
    float* S2 = (float*)carve(NND * 4);
    float* score = (float*)carve(EFE * 4);

    auto scan = [&](const int* in, int* outp, int* totalDst) {
        scan1<<<NSCAN_B, SCAN_BS, 0, stream>>>(in, outp, bsums, NND);
        scan2<<<1, 128, 0, stream>>>(bsums, NSCAN_B);
        scan3<<<NSCAN_B, SCAN_BS, 0, stream>>>(outp, bsums, NND, NSCAN_B, totalDst);
    };

    // zero state: one memset for all zero-init scratch, plus minOkey=0xFF and d_out=0
    hipMemsetAsync(zero0, 0, zeroBytes, stream);
    hipMemsetAsync(minOkey, 0xFF, NND * 8, stream);
    hipMemsetAsync(d_out, 0, (size_t)out_size * 4, stream);

    // clean edge list (sorted by (u,v), deduped)
    kFilterCount<<<NB_EU, 256, 0, stream>>>(ei, cnt);
    scan(cnt, offA, scal + 15);
    kFilterScatter<<<NB_EU, 256, 0, stream>>>(ei, offA, tmp, bucketV);
    kSortSeg<<<NB_N, 256, 0, stream>>>(bucketV, offA);
    kUniqueCount<<<NB_N, 256, 0, stream>>>(bucketV, offA, ucnt);
    scan(ucnt, uoff, scal + 0);  // scal[0] = E
    kCompact<<<NB_N, 256, 0, stream>>>(bucketV, offA, uoff, eU, eV);

    // incidence CSR (sorted -> deterministic gathers)
    kIncCount<<<NB_EF, 256, 0, stream>>>(eU, eV, scal, icnt);
    scan(icnt, ioff, scal + 15);
    kIncScatter<<<NB_EF, 256, 0, stream>>>(eU, eV, scal, ioff, itmp, ilist);
    kSortSeg<<<NB_N, 256, 0, stream>>>(ilist, ioff);
    kDinv<<<NB_EF, 256, 0, stream>>>(eU, eV, icnt, scal, dinv);

    // conv1
    kGemm<<<(EFE + GEB - 1) / GEB, 256, 0, stream>>>(x, W1, eU, eV, scal, h);
    kSGather<<<NND, HIDC, 0, stream>>>(h, dinv, ioff, ilist, Snode);
    kConv1<<<NB_E64, 256, 0, stream>>>(h, Snode, dinv, eU, eV, b1, scal, h2);

    // batch-norm stats + fused norm/relu/dot(W2)
    kRed1<<<NCHAIN / 4, 256, 0, stream>>>(h2, scal, muvar, partial, 0);
    kRed2<<<1, 256, 0, stream>>>(partial, scal, muvar, 0);
    kRed1<<<NCHAIN / 4, 256, 0, stream>>>(h2, scal, muvar, partial, 1);
    kRed2<<<1, 256, 0, stream>>>(partial, scal, muvar, 1);
    kNormZ<<<NB_E64, 256, 0, stream>>>(h2, muvar, gamma1, beta1, W2, scal, zArr);

    // conv2 -> scores + sortable keys
    kS2<<<NB_N, 256, 0, stream>>>(zArr, dinv, ioff, ilist, S2);
    kScore<<<NB_EF, 256, 0, stream>>>(zArr, S2, dinv, eU, eV, b2, scal, score, okey);

    // exact k-th largest via 8x8-bit radix select
    kSelInit<<<1, 1, 0, stream>>>(scal, scal + 1, dpref);
    for (int p = 0; p < 8; p++) {
        int shift = 56 - 8 * p;
        u64 maskHi = (p == 0) ? 0ULL : ((~0ULL) << (shift + 8));
        kHist<<<HIST_BLOCKS, 256, 0, stream>>>(okey, scal, hist, dpref, maskHi, shift);
        kSelPass<<<1, 256, 0, stream>>>(hist, dpref, scal + 1, shift);
    }

    // cluster: per-dst last-in-topk-order edge
    kMinKey<<<NB_EF, 256, 0, stream>>>(okey, eV, scal, dpref, minOkey);
    kN2cInit<<<NB_N, 256, 0, stream>>>(n2c);
    kN2cSet<<<NB_EF, 256, 0, stream>>>(okey, eU, eV, scal, dpref, minOkey, n2c);
    kPresent<<<NB_N, 256, 0, stream>>>(n2c, present);
    scan(present, o2n, scal + 2);  // scal[2] = M
    kNi<<<NB_N, 256, 0, stream>>>(n2c, o2n, niArr);

    // pooled features (x_pool lives at d_out offset 0; d_out zeroed upfront)
    kCcnt<<<NB_N, 256, 0, stream>>>(niArr, ccnt);
    kXacc<<<NB_X, 256, 0, stream>>>(x, niArr, dout);
    kXdiv<<<NB_X, 256, 0, stream>>>(dout, ccnt, scal);

    // pooled edges
    kCEcount<<<NB_EU, 256, 0, stream>>>(ei, niArr, ecnt2);
    scan(ecnt2, eoff2, scal + 4);
    kCEscatter<<<NB_EU, 256, 0, stream>>>(ei, niArr, eoff2, etmp2, bkD);
    kRankSort<<<NND, 64, 0, stream>>>(bkD, bkD2, eoff2, uecnt);
    scan(uecnt, ueoff, scal + 3);  // scal[3] = Ep
    kCEwrite<<<NB_N, 256, 0, stream>>>(bkD2, eoff2, ueoff, scal, dout);

    // batch_pool, scores, ni
    kBatchPool<<<NB_N, 256, 0, stream>>>(batch, present, o2n, scal, dout);
    kScoresOut<<<NB_EF, 256, 0, stream>>>(score, scal, dout);
    kNiOut<<<NB_N, 256, 0, stream>>>(niArr, scal, dout);
}

// Round 5
// 483.682 us; speedup vs baseline: 3.3467x; 1.0854x over previous
//
#include <hip/hip_runtime.h>
#include <stdint.h>

typedef unsigned long long u64;
typedef unsigned int u32;

#define NND 20000      // nodes
#define EUA 160000     // directed input edges (2 * E_UND)
#define EFE 80000      // max clean (undirected, deduped) edges
#define ICH 128
#define HIDC 64
#define SCAN_BS 256
#define NB_N ((NND + 255) / 256)
#define NB_EU ((EUA + 255) / 256)
#define NB_EF ((EFE + 255) / 256)
#define NB_E64 ((EFE * HIDC + 255) / 256)
#define NB_X ((NND * ICH + 255) / 256)
#define NSCAN_B ((NND + SCAN_BS - 1) / SCAN_BS)
#define HIST_BLOCKS 128
#define GEB 64         // edges per gemm block
#define XS_PAD 132     // xs leading-dim pad
#define NCHAIN 4096    // mean/var reduction chains
// max live output extent: M*128 + 2*Ep + M + E + N <= 3,000,000 floats
#define OUT_MAX_INIT 3000000

// scal slots: 0=E, 1=kRem, 2=M, 3=Ep, 4=Ekept, 15=dummy

// ---------------- scan (exclusive, n = NND fixed) ----------------
__global__ void scan1(const int* __restrict__ in, int* __restrict__ out,
                      int* __restrict__ bsums, int n) {
    __shared__ int sh[SCAN_BS];
    int tid = threadIdx.x;
    int i = blockIdx.x * SCAN_BS + tid;
    int v = (i < n) ? in[i] : 0;
    sh[tid] = v;
    __syncthreads();
    for (int o = 1; o < SCAN_BS; o <<= 1) {
        int t = (tid >= o) ? sh[tid - o] : 0;
        __syncthreads();
        sh[tid] += t;
        __syncthreads();
    }
    if (i < n) out[i] = sh[tid] - v;  // exclusive
    if (tid == SCAN_BS - 1) bsums[blockIdx.x] = sh[tid];
}
__global__ void scan2(int* __restrict__ bsums, int nb) {
    __shared__ int sh[160];
    int tid = threadIdx.x;
    if (tid < nb) sh[tid] = bsums[tid];
    __syncthreads();
    if (tid == 0) {
        int acc = 0;
        for (int i = 0; i < nb; i++) { int t = sh[i]; sh[i] = acc; acc += t; }
        sh[nb] = acc;
    }
    __syncthreads();
    if (tid <= nb) bsums[tid] = sh[tid];
}
__global__ void scan3(int* __restrict__ out, const int* __restrict__ bsums,
                      int n, int nb, int* __restrict__ totalDst) {
    int i = blockIdx.x * SCAN_BS + threadIdx.x;
    if (i < n) out[i] += bsums[blockIdx.x];
    if (i == 0) {
        int tot = bsums[nb];
        out[n] = tot;
        *totalDst = tot;
    }
}

// ---------------- clean edge build ----------------
__global__ void kFilterCount(const int* __restrict__ ei, int* __restrict__ cnt) {
    int i = blockIdx.x * 256 + threadIdx.x;
    if (i >= EUA) return;
    int s = ei[i], d = ei[EUA + i];
    if (s < d) atomicAdd(&cnt[s], 1);
}
__global__ void kFilterScatter(const int* __restrict__ ei, const int* __restrict__ offA,
                               int* __restrict__ tmp, int* __restrict__ bucketV) {
    int i = blockIdx.x * 256 + threadIdx.x;
    if (i >= EUA) return;
    int s = ei[i], d = ei[EUA + i];
    if (s < d) {
        int p = offA[s] + atomicAdd(&tmp[s], 1);
        bucketV[p] = d;
    }
}
// wave-parallel rank sort per bucket + unique count (ascending order ==
// what insertion sort produced -> downstream bitwise identical).
__global__ void kRankSort(const int* __restrict__ in, int* __restrict__ out,
                          const int* __restrict__ offA, int* __restrict__ ucnt) {
    int a = blockIdx.x;
    int s = offA[a], e = offA[a + 1], len = e - s;
    for (int j = threadIdx.x; j < len; j += 64) {
        int v = in[s + j];
        int r = 0;
        for (int i = 0; i < len; i++) {
            int w = in[s + i];
            r += (w < v) || (w == v && i < j);
        }
        out[s + r] = v;
    }
    __syncthreads();
    int c = 0;
    for (int j = threadIdx.x; j < len; j += 64)
        c += (j == 0) || (out[s + j] != out[s + j - 1]);
#pragma unroll
    for (int o = 32; o > 0; o >>= 1) c += __shfl_down(c, o, 64);
    if (threadIdx.x == 0) ucnt[a] = c;
}
__global__ void kCompact(const int* __restrict__ arr, const int* __restrict__ offA,
                         const int* __restrict__ uoff, int* __restrict__ eU,
                         int* __restrict__ eV) {
    int u = blockIdx.x * 256 + threadIdx.x;
    if (u >= NND) return;
    int s = offA[u], e = offA[u + 1], o = uoff[u];
    for (int i = s; i < e; i++)
        if (i == s || arr[i] != arr[i - 1]) { eU[o] = u; eV[o] = arr[i]; o++; }
}

// ---------------- incidence CSR ----------------
__global__ void kIncCount(const int* __restrict__ eU, const int* __restrict__ eV,
                          const int* __restrict__ scal, int* __restrict__ icnt) {
    int e = blockIdx.x * 256 + threadIdx.x;
    if (e >= scal[0]) return;
    atomicAdd(&icnt[eU[e]], 1);
    atomicAdd(&icnt[eV[e]], 1);
}
__global__ void kIncScatter(const int* __restrict__ eU, const int* __restrict__ eV,
                            const int* __restrict__ scal, const int* __restrict__ ioff,
                            int* __restrict__ itmp, int* __restrict__ ilist) {
    int e = blockIdx.x * 256 + threadIdx.x;
    if (e >= scal[0]) return;
    int u = eU[e], v = eV[e];
    ilist[ioff[u] + atomicAdd(&itmp[u], 1)] = e;
    ilist[ioff[v] + atomicAdd(&itmp[v], 1)] = e;
}
__global__ void kDinv(const int* __restrict__ eU, const int* __restrict__ eV,
                      const int* __restrict__ icnt, const int* __restrict__ scal,
                      float* __restrict__ dinv) {
    int e = blockIdx.x * 256 + threadIdx.x;
    if (e >= scal[0]) return;
    dinv[e] = rsqrtf((float)(icnt[eU[e]] + icnt[eV[e]] - 1));
}

// ---------------- GEMM: h = (0.5*(x[u]+x[v])) @ W1 ----------------
__global__ void kGemm(const float* __restrict__ x, const float* __restrict__ W1,
                      const int* __restrict__ eU, const int* __restrict__ eV,
                      const int* __restrict__ scal, float* __restrict__ h) {
    __shared__ float W1s[ICH][HIDC];
    __shared__ float xs[GEB][XS_PAD];
    int t = threadIdx.x;
    int E = scal[0];
    int e0 = blockIdx.x * GEB;
    if (e0 >= E) return;

    {
        const float4* Wv = (const float4*)W1;
        float4* Ws = (float4*)&W1s[0][0];
        for (int i = t; i < ICH * HIDC / 4; i += 256) Ws[i] = Wv[i];
    }
    {
        int eb = t >> 2, q = t & 3;
        int e = e0 + eb;
        if (e < E) {
            int u = eU[e], v = eV[e];
            const float4* xu = (const float4*)(x + (size_t)u * ICH) + q * 8;
            const float4* xv = (const float4*)(x + (size_t)v * ICH) + q * 8;
            float* xd = &xs[eb][q * 32];
#pragma unroll
            for (int i = 0; i < 8; i++) {
                float4 a = xu[i], b = xv[i];
                xd[i * 4 + 0] = 0.5f * (a.x + b.x);
                xd[i * 4 + 1] = 0.5f * (a.y + b.y);
                xd[i * 4 + 2] = 0.5f * (a.z + b.z);
                xd[i * 4 + 3] = 0.5f * (a.w + b.w);
            }
        }
    }
    __syncthreads();

    int cg4 = (t & 15) * 4;
    int es = t >> 4;
    float a00=0,a01=0,a02=0,a03=0, a10=0,a11=0,a12=0,a13=0;
    float a20=0,a21=0,a22=0,a23=0, a30=0,a31=0,a32=0,a33=0;
#pragma unroll 4
    for (int k = 0; k < ICH; k++) {
        float4 wv = *(const float4*)&W1s[k][cg4];
        float x0 = xs[es][k], x1 = xs[es + 16][k];
        float x2 = xs[es + 32][k], x3 = xs[es + 48][k];
        a00 += x0 * wv.x; a01 += x0 * wv.y; a02 += x0 * wv.z; a03 += x0 * wv.w;
        a10 += x1 * wv.x; a11 += x1 * wv.y; a12 += x1 * wv.z; a13 += x1 * wv.w;
        a20 += x2 * wv.x; a21 += x2 * wv.y; a22 += x2 * wv.z; a23 += x2 * wv.w;
        a30 += x3 * wv.x; a31 += x3 * wv.y; a32 += x3 * wv.z; a33 += x3 * wv.w;
    }
    int e;
    e = e0 + es;
    if (e < E) *(float4*)&h[(size_t)e * HIDC + cg4] = make_float4(a00, a01, a02, a03);
    e = e0 + es + 16;
    if (e < E) *(float4*)&h[(size_t)e * HIDC + cg4] = make_float4(a10, a11, a12, a13);
    e = e0 + es + 32;
    if (e < E) *(float4*)&h[(size_t)e * HIDC + cg4] = make_float4(a20, a21, a22, a23);
    e = e0 + es + 48;
    if (e < E) *(float4*)&h[(size_t)e * HIDC + cg4] = make_float4(a30, a31, a32, a33);
}

// S[n][c] = sum over incident edges e: h[e][c]*dinv[e]  (deterministic gather)
__global__ void kSGather(const float* __restrict__ h, const float* __restrict__ dinv,
                         const int* __restrict__ ioff, const int* __restrict__ ilist,
                         float* __restrict__ S) {
    int n = blockIdx.x;
    int c = threadIdx.x;
    int s = ioff[n], e = ioff[n + 1];
    float acc = 0.f;
    for (int j = s; j < e; j++) {
        int ed = ilist[j];
        acc += h[(size_t)ed * HIDC + c] * dinv[ed];
    }
    S[(size_t)n * HIDC + c] = acc;
}
__global__ void kConv1(const float* __restrict__ h, const float* __restrict__ S,
                       const float* __restrict__ dinv, const int* __restrict__ eU,
                       const int* __restrict__ eV, const float* __restrict__ b1,
                       const int* __restrict__ scal, float* __restrict__ h2) {
    int idx = blockIdx.x * 256 + threadIdx.x;
    int e = idx >> 6;
    if (e >= scal[0]) return;
    int c = idx & 63;
    float a = dinv[e];
    h2[idx] = a * (S[(size_t)eU[e] * HIDC + c] + S[(size_t)eV[e] * HIDC + c]) -
              a * a * h[idx] + b1[c];
}

// ---------------- mean/var (deterministic, 4096-chain tree) ----------------
__global__ void kRed1(const float* __restrict__ h2, const int* __restrict__ scal,
                      const float* __restrict__ muvar, float* __restrict__ partial,
                      int pass) {
    int t = threadIdx.x;
    int g = blockIdx.x * 4 + (t >> 6);
    int c = t & 63;
    int E = scal[0];
    float m = pass ? muvar[c] : 0.f;
    float acc = 0.f;
    for (int e = g; e < E; e += NCHAIN) {
        float v = h2[(size_t)e * HIDC + c];
        if (pass) { float d = v - m; acc += d * d; }
        else acc += v;
    }
    partial[g * HIDC + c] = acc;
}
__global__ void kRed2(const float* __restrict__ partial, const int* __restrict__ scal,
                      float* __restrict__ muvar, int pass) {
    __shared__ float sh[4][HIDC];
    int t = threadIdx.x;
    int q = t >> 6, c = t & 63;
    float acc = 0.f;
    int g0 = q * (NCHAIN / 4);
    for (int g = g0; g < g0 + NCHAIN / 4; g++) acc += partial[g * HIDC + c];
    sh[q][c] = acc;
    __syncthreads();
    if (q == 0) {
        float s = ((sh[0][c] + sh[1][c]) + sh[2][c]) + sh[3][c];
        muvar[pass * HIDC + c] = s / (float)scal[0];
    }
}
// fused batchnorm+relu+dot(W2)
__global__ void kNormZ(const float* __restrict__ h2, const float* __restrict__ muvar,
                       const float* __restrict__ gamma1, const float* __restrict__ beta1,
                       const float* __restrict__ W2, const int* __restrict__ scal,
                       float* __restrict__ z) {
    int idx = blockIdx.x * 256 + threadIdx.x;
    int e = idx >> 6;
    if (e >= scal[0]) return;
    int c = idx & 63;
    float t = gamma1[c] * (h2[idx] - muvar[c]) * rsqrtf(muvar[HIDC + c] + 1e-5f) + beta1[c];
    t = t > 0.f ? t : 0.f;
    float p = t * W2[c];
#pragma unroll
    for (int o = 32; o > 0; o >>= 1) p += __shfl_down(p, o, 64);
    if (c == 0) z[e] = p;
}
__global__ void kS2(const float* __restrict__ z, const float* __restrict__ dinv,
                    const int* __restrict__ ioff, const int* __restrict__ ilist,
                    float* __restrict__ S2) {
    int n = blockIdx.x * 256 + threadIdx.x;
    if (n >= NND) return;
    float acc = 0.f;
    for (int j = ioff[n]; j < ioff[n + 1]; j++) {
        int e = ilist[j];
        acc += z[e] * dinv[e];
    }
    S2[n] = acc;
}
__global__ void kScore(const float* __restrict__ z, const float* __restrict__ S2,
                       const float* __restrict__ dinv, const int* __restrict__ eU,
                       const int* __restrict__ eV, const float* __restrict__ b2,
                       const int* __restrict__ scal, float* __restrict__ score,
                       u64* __restrict__ okey) {
    int e = blockIdx.x * 256 + threadIdx.x;
    if (e >= scal[0]) return;
    float a = dinv[e];
    float l = a * (S2[eU[e]] + S2[eV[e]]) - a * a * z[e] + b2[0];
    float s = 1.f / (1.f + expf(-l));
    score[e] = s;
    u32 b = __float_as_uint(s);
    b = (b >> 31) ? ~b : (b | 0x80000000u);
    okey[e] = (((u64)b) << 32) | (u32)(0xFFFFFFFFu - (u32)e);
}

// ---------------- radix select (k-th largest okey) ----------------
__global__ void kSelInit(const int* __restrict__ scal, int* __restrict__ krem,
                         u64* __restrict__ pref) {
    int E = scal[0];
    int k = E / 2;
    if (k > NND / 2) k = NND / 2;
    if (k < 1) k = 1;
    *krem = k;
    *pref = 0ULL;
}
__global__ void kHist(const u64* __restrict__ okey, const int* __restrict__ scal,
                      int* __restrict__ hist, const u64* __restrict__ pref,
                      u64 maskHi, int shift) {
    __shared__ int sh[256];
    sh[threadIdx.x] = 0;
    __syncthreads();
    int E = scal[0];
    u64 p = *pref;
    for (int e = blockIdx.x * 256 + threadIdx.x; e < E; e += HIST_BLOCKS * 256) {
        u64 k = okey[e];
        if ((k & maskHi) == p)
            atomicAdd(&sh[(int)((k >> shift) & 255ULL)], 1);
    }
    __syncthreads();
    int v = sh[threadIdx.x];
    if (v) atomicAdd(&hist[threadIdx.x], v);
}
__global__ void kSelPass(int* __restrict__ hist, u64* __restrict__ pref,
                         int* __restrict__ krem, int shift) {
    __shared__ int sh[256];
    sh[threadIdx.x] = hist[threadIdx.x];
    __syncthreads();
    hist[threadIdx.x] = 0;
    if (threadIdx.x == 0) {
        int kr = *krem;
        int cumAbove = 0;
        int b = 255;
        for (; b >= 0; b--) {
            int hcnt = sh[b];
            if (cumAbove + hcnt >= kr) break;
            cumAbove += hcnt;
        }
        if (b < 0) b = 0;
        *krem = kr - cumAbove;
        *pref |= ((u64)b) << shift;
    }
}

// ---------------- clustering ----------------
__global__ void kN2cInit(int* __restrict__ n2c) {
    int n = blockIdx.x * 256 + threadIdx.x;
    if (n < NND) n2c[n] = n;
}
__global__ void kMinKey(const u64* __restrict__ okey, const int* __restrict__ eV,
                        const int* __restrict__ scal, const u64* __restrict__ pref,
                        u64* __restrict__ minOkey) {
    int e = blockIdx.x * 256 + threadIdx.x;
    if (e >= scal[0]) return;
    u64 k = okey[e];
    if (k >= *pref) atomicMin(&minOkey[eV[e]], k);
}
__global__ void kN2cSet(const u64* __restrict__ okey, const int* __restrict__ eU,
                        const int* __restrict__ eV, const int* __restrict__ scal,
                        const u64* __restrict__ pref, const u64* __restrict__ minOkey,
                        int* __restrict__ n2c) {
    int e = blockIdx.x * 256 + threadIdx.x;
    if (e >= scal[0]) return;
    u64 k = okey[e];
    int v = eV[e];
    if (k >= *pref && k == minOkey[v]) n2c[v] = eU[e];
}
__global__ void kPresent(const int* __restrict__ n2c, int* __restrict__ present) {
    int n = blockIdx.x * 256 + threadIdx.x;
    if (n < NND) present[n2c[n]] = 1;
}
__global__ void kNi(const int* __restrict__ n2c, const int* __restrict__ o2n,
                    int* __restrict__ ni) {
    int n = blockIdx.x * 256 + threadIdx.x;
    if (n < NND) ni[n] = o2n[n2c[n]];
}

// ---------------- pooled features ----------------
__global__ void kCcnt(const int* __restrict__ ni, int* __restrict__ ccnt) {
    int n = blockIdx.x * 256 + threadIdx.x;
    if (n < NND) atomicAdd(&ccnt[ni[n]], 1);
}
__global__ void kXacc(const float* __restrict__ x, const int* __restrict__ ni,
                      float* __restrict__ dout) {
    int idx = blockIdx.x * 256 + threadIdx.x;
    if (idx >= NND * ICH) return;
    int n = idx >> 7, c = idx & 127;
    atomicAdd(&dout[(size_t)ni[n] * ICH + c], x[idx]);
}
__global__ void kXdiv(float* __restrict__ dout, const int* __restrict__ ccnt,
                      const int* __restrict__ scal) {
    int idx = blockIdx.x * 256 + threadIdx.x;
    int m = idx >> 7;
    if (m >= scal[2]) return;
    dout[idx] /= (float)ccnt[m];
}

// ---------------- pooled edges ----------------
__global__ void kCEcount(const int* __restrict__ ei, const int* __restrict__ ni,
                         int* __restrict__ ecnt2) {
    int i = blockIdx.x * 256 + threadIdx.x;
    if (i >= EUA) return;
    int a = ni[ei[i]], b = ni[ei[EUA + i]];
    if (a != b) atomicAdd(&ecnt2[a], 1);
}
__global__ void kCEscatter(const int* __restrict__ ei, const int* __restrict__ ni,
                           const int* __restrict__ eoff2, int* __restrict__ etmp2,
                           int* __restrict__ bkD) {
    int i = blockIdx.x * 256 + threadIdx.x;
    if (i >= EUA) return;
    int a = ni[ei[i]], b = ni[ei[EUA + i]];
    if (a != b) {
        int p = eoff2[a] + atomicAdd(&etmp2[a], 1);
        bkD[p] = b;
    }
}
__global__ void kCEwrite(const int* __restrict__ bkD2, const int* __restrict__ offA,
                         const int* __restrict__ ueoff, const int* __restrict__ scal,
                         float* __restrict__ dout) {
    int a = blockIdx.x * 256 + threadIdx.x;
    if (a >= NND) return;
    int s = offA[a], e = offA[a + 1];
    int M = scal[2], Ep = scal[3];
    float* r0 = dout + (size_t)M * ICH;
    float* r1 = r0 + Ep;
    int o = ueoff[a];
    for (int i = s; i < e; i++)
        if (i == s || bkD2[i] != bkD2[i - 1]) {
            r0[o] = (float)a;
            r1[o] = (float)bkD2[i];
            o++;
        }
}

// ---------------- trailing outputs ----------------
__global__ void kBatchPool(const int* __restrict__ batch, const int* __restrict__ present,
                           const int* __restrict__ o2n, const int* __restrict__ scal,
                           float* __restrict__ dout) {
    int n = blockIdx.x * 256 + threadIdx.x;
    if (n >= NND) return;
    if (present[n]) {
        size_t base = (size_t)scal[2] * ICH + 2 * (size_t)scal[3];
        dout[base + o2n[n]] = (float)batch[n];
    }
}
__global__ void kScoresOut(const float* __restrict__ score, const int* __restrict__ scal,
                           float* __restrict__ dout) {
    int e = blockIdx.x * 256 + threadIdx.x;
    if (e >= scal[0]) return;
    size_t base = (size_t)scal[2] * ICH + 2 * (size_t)scal[3] + scal[2];
    dout[base + e] = score[e];
}
__global__ void kNiOut(const int* __restrict__ ni, const int* __restrict__ scal,
                       float* __restrict__ dout) {
    int n = blockIdx.x * 256 + threadIdx.x;
    if (n >= NND) return;
    size_t base = (size_t)scal[2] * ICH + 2 * (size_t)scal[3] + scal[2] + scal[0];
    dout[base + n] = (float)ni[n];
}

extern "C" void kernel_launch(void* const* d_in, const int* in_sizes, int n_in,
                              void* d_out, int out_size, void* d_ws, size_t ws_size,
                              hipStream_t stream) {
    (void)in_sizes; (void)n_in; (void)ws_size;
    const float* x = (const float*)d_in[0];
    const float* W1 = (const float*)d_in[1];
    const float* b1 = (const float*)d_in[2];
    const float* gamma1 = (const float*)d_in[3];
    const float* beta1 = (const float*)d_in[4];
    const float* W2 = (const float*)d_in[5];
    const float* b2 = (const float*)d_in[6];
    const int* ei = (const int*)d_in[7];
    const int* batch = (const int*)d_in[8];
    float* dout = (float*)d_out;

    char* w = (char*)d_ws;
    size_t off = 0;
    auto carve = [&](size_t bytes) -> void* {
        off = (off + 255) & ~(size_t)255;
        void* p = w + off;
        off += bytes;
        return p;
    };
    // ---- contiguous zero-init region (ONE memset covers all of these) ----
    char* zero0 = w;
    int* cnt = (int*)carve(NND * 4);
    int* tmp = (int*)carve(NND * 4);
    int* icnt = (int*)carve(NND * 4);
    int* itmp = (int*)carve(NND * 4);
    int* present = (int*)carve(NND * 4);
    int* ccnt = (int*)carve(NND * 4);
    int* ecnt2 = (int*)carve(NND * 4);
    int* etmp2 = (int*)carve(NND * 4);
    int* scal = (int*)carve(16 * 4);
    int* hist = (int*)carve(256 * 4);
    size_t zeroBytes = off;
    // ---- rest ----
    int* offA = (int*)carve((NND + 2) * 4);
    int* ucnt = (int*)carve(NND * 4);
    int* uoff = (int*)carve((NND + 2) * 4);
    int* ioff = (int*)carve((NND + 2) * 4);
    int* bsums = (int*)carve((NSCAN_B + 2) * 4);
    int* n2c = (int*)carve(NND * 4);
    int* o2n = (int*)carve((NND + 2) * 4);
    int* niArr = (int*)carve(NND * 4);
    int* eoff2 = (int*)carve((NND + 2) * 4);
    int* uecnt = (int*)carve(NND * 4);
    int* ueoff = (int*)carve((NND + 2) * 4);
    int* bucketV = (int*)carve(EUA * 4);
    int* bucketS = (int*)carve(EUA * 4);    // rank-sorted bucketV
    int* eU = (int*)carve(EFE * 4);
    int* eV = (int*)carve(EFE * 4);
    int* ilist = (int*)carve(2 * EFE * 4);
    int* ilistS = (int*)carve(2 * EFE * 4); // rank-sorted ilist
    int* bkD = (int*)carve(EUA * 4);
    int* bkD2 = (int*)carve(EUA * 4);
    u64* okey = (u64*)carve(EFE * 8);
    u64* minOkey = (u64*)carve(NND * 8);
    u64* dpref = (u64*)carve(8);
    float* dinv = (float*)carve(EFE * 4);
    float* h = (float*)carve((size_t)EFE * HIDC * 4);
    float* h2 = (float*)carve((size_t)EFE * HIDC * 4);
    float* Snode = (float*)carve((size_t)NND * HIDC * 4);
    float* partial = (float*)carve((size_t)NCHAIN * HIDC * 4);
    float* muvar = (float*)carve(128 * 4);
    float* zArr = (float*)carve(EFE * 4);
    float* S2 = (float*)carve(NND * 4);
    float* score = (float*)carve(EFE * 4);

    auto scan = [&](const int* in, int* outp, int* totalDst) {
        scan1<<<NSCAN_B, SCAN_BS, 0, stream>>>(in, outp, bsums, NND);
        scan2<<<1, 128, 0, stream>>>(bsums, NSCAN_B);
        scan3<<<NSCAN_B, SCAN_BS, 0, stream>>>(outp, bsums, NND, NSCAN_B, totalDst);
    };

    // zero state. d_out: only the live prefix can ever be read/validated
    // (M*128 + 2*Ep + M + E + N <= OUT_MAX_INIT) -- was zeroing 268 MB.
    size_t outInit = (size_t)out_size;
    if (outInit > OUT_MAX_INIT) outInit = OUT_MAX_INIT;
    hipMemsetAsync(zero0, 0, zeroBytes, stream);
    hipMemsetAsync(minOkey, 0xFF, NND * 8, stream);
    hipMemsetAsync(d_out, 0, outInit * 4, stream);

    // clean edge list (sorted by (u,v), deduped); rank-sort also emits ucnt
    kFilterCount<<<NB_EU, 256, 0, stream>>>(ei, cnt);
    scan(cnt, offA, scal + 15);
    kFilterScatter<<<NB_EU, 256, 0, stream>>>(ei, offA, tmp, bucketV);
    kRankSort<<<NND, 64, 0, stream>>>(bucketV, bucketS, offA, ucnt);
    scan(ucnt, uoff, scal + 0);  // scal[0] = E
    kCompact<<<NB_N, 256, 0, stream>>>(bucketS, offA, uoff, eU, eV);

    // incidence CSR (rank-sorted -> same ascending order as before)
    kIncCount<<<NB_EF, 256, 0, stream>>>(eU, eV, scal, icnt);
    scan(icnt, ioff, scal + 15);
    kIncScatter<<<NB_EF, 256, 0, stream>>>(eU, eV, scal, ioff, itmp, ilist);
    kRankSort<<<NND, 64, 0, stream>>>(ilist, ilistS, ioff, tmp);  // tmp = dummy ucnt
    kDinv<<<NB_EF, 256, 0, stream>>>(eU, eV, icnt, scal, dinv);

    // conv1
    kGemm<<<(EFE + GEB - 1) / GEB, 256, 0, stream>>>(x, W1, eU, eV, scal, h);
    kSGather<<<NND, HIDC, 0, stream>>>(h, dinv, ioff, ilistS, Snode);
    kConv1<<<NB_E64, 256, 0, stream>>>(h, Snode, dinv, eU, eV, b1, scal, h2);

    // batch-norm stats + fused norm/relu/dot(W2)
    kRed1<<<NCHAIN / 4, 256, 0, stream>>>(h2, scal, muvar, partial, 0);
    kRed2<<<1, 256, 0, stream>>>(partial, scal, muvar, 0);
    kRed1<<<NCHAIN / 4, 256, 0, stream>>>(h2, scal, muvar, partial, 1);
    kRed2<<<1, 256, 0, stream>>>(partial, scal, muvar, 1);
    kNormZ<<<NB_E64, 256, 0, stream>>>(h2, muvar, gamma1, beta1, W2, scal, zArr);

    // conv2 -> scores + sortable keys
    kS2<<<NB_N, 256, 0, stream>>>(zArr, dinv, ioff, ilistS, S2);
    kScore<<<NB_EF, 256, 0, stream>>>(zArr, S2, dinv, eU, eV, b2, scal, score, okey);

    // exact k-th largest via 8x8-bit radix select
    kSelInit<<<1, 1, 0, stream>>>(scal, scal + 1, dpref);
    for (int p = 0; p < 8; p++) {
        int shift = 56 - 8 * p;
        u64 maskHi = (p == 0) ? 0ULL : ((~0ULL) << (shift + 8));
        kHist<<<HIST_BLOCKS, 256, 0, stream>>>(okey, scal, hist, dpref, maskHi, shift);
        kSelPass<<<1, 256, 0, stream>>>(hist, dpref, scal + 1, shift);
    }

    // cluster: per-dst last-in-topk-order edge
    kMinKey<<<NB_EF, 256, 0, stream>>>(okey, eV, scal, dpref, minOkey);
    kN2cInit<<<NB_N, 256, 0, stream>>>(n2c);
    kN2cSet<<<NB_EF, 256, 0, stream>>>(okey, eU, eV, scal, dpref, minOkey, n2c);
    kPresent<<<NB_N, 256, 0, stream>>>(n2c, present);
    scan(present, o2n, scal + 2);  // scal[2] = M
    kNi<<<NB_N, 256, 0, stream>>>(n2c, o2n, niArr);

    // pooled features (x_pool lives at d_out offset 0; prefix zeroed upfront)
    kCcnt<<<NB_N, 256, 0, stream>>>(niArr, ccnt);
    kXacc<<<NB_X, 256, 0, stream>>>(x, niArr, dout);
    kXdiv<<<NB_X, 256, 0, stream>>>(dout, ccnt, scal);

    // pooled edges
    kCEcount<<<NB_EU, 256, 0, stream>>>(ei, niArr, ecnt2);
    scan(ecnt2, eoff2, scal + 4);
    kCEscatter<<<NB_EU, 256, 0, stream>>>(ei, niArr, eoff2, etmp2, bkD);
    kRankSort<<<NND, 64, 0, stream>>>(bkD, bkD2, eoff2, uecnt);
    scan(uecnt, ueoff, scal + 3);  // scal[3] = Ep
    kCEwrite<<<NB_N, 256, 0, stream>>>(bkD2, eoff2, ueoff, scal, dout);

    // batch_pool, scores, ni
    kBatchPool<<<NB_N, 256, 0, stream>>>(batch, present, o2n, scal, dout);
    kScoresOut<<<NB_EF, 256, 0, stream>>>(score, scal, dout);
    kNiOut<<<NB_N, 256, 0, stream>>>(niArr, scal, dout);
}